// Round 6
// baseline (2905.398 us; speedup 1.0000x reference)
//
#include <hip/hip_runtime.h>
#include <hip/hip_bf16.h>

#define B_ 8
#define S_ 4096
#define F_ 256
#define I_ 512
#define D_ 4
#define K_ 7
#define V_ 256
#define I3_ 1536
#define KE_ 3584           // 7*512 flattened causal-conv K
#define VR_ (S_ + 8)       // vbt rows: 6 zero-pad + 4096 + 2 slack

using bf16 = __hip_bfloat16;
typedef __bf16 bf16x8 __attribute__((ext_vector_type(8)));
typedef float  f32x4  __attribute__((ext_vector_type(4)));

#define LDS_PTR(p) ((__attribute__((address_space(3))) void*)(p))
#define GLB_PTR(p) ((const __attribute__((address_space(1))) void*)(p))

// mish(x) = x*tanh(softplus(x)) = x*(u^2+2u)/(u^2+2u+2), u=e^x (exact closed form).
__device__ __forceinline__ float mishf(float x) {
    float u = expf(fminf(x, 30.0f));
    float t = u * (u + 2.0f);
    return x * (t / (t + 2.0f));
}

__device__ __forceinline__ float loadw(const void* p, size_t i, int isbf) {
    return isbf ? __bfloat162float(((const bf16*)p)[i]) : ((const float*)p)[i];
}

__device__ __forceinline__ __bf16 tobf(float x) {
    bf16 h = __float2bfloat16(x);
    return *(__bf16*)&h;
}

// bf16 buffers of small weights never show bf16-exponent>=132 (|x|>=32);
// fp32 buffers read as uint16 do (random mantissa bits in low halves).
__global__ __launch_bounds__(256)
void detect_kernel(int* __restrict__ flag, const unsigned short* __restrict__ p)
{
    __shared__ int sh[256];
    int cnt = 0;
    for (int j = threadIdx.x; j < 16384; j += 256) {
        unsigned int e = (p[j] >> 7) & 0xffu;
        if (e >= 132u) cnt++;
    }
    sh[threadIdx.x] = cnt;
    __syncthreads();
    for (int s = 128; s > 0; s >>= 1) {
        if ((int)threadIdx.x < s) sh[threadIdx.x] += sh[threadIdx.x + s];
        __syncthreads();
    }
    if (threadIdx.x == 0) flag[0] = (sh[0] == 0) ? 1 : 0;   // 1 => bf16 inputs
}

__global__ __launch_bounds__(256)
void embed_kernel(float* __restrict__ x0, float* __restrict__ x1,
                  const int* __restrict__ inp, const void* __restrict__ emb,
                  const int* __restrict__ flag)
{
    const int isbf = flag[0];
    size_t idx = (size_t)blockIdx.x * 256 + threadIdx.x;   // over B*F*S
    int s = (int)(idx % S_);
    int f = (int)((idx / S_) % F_);
    int b = (int)(idx / ((size_t)S_ * F_));
    int tok = inp[b * S_ + s];
    x0[idx] = loadw(emb, (size_t)tok * (2 * F_) + f, isbf);
    x1[idx] = loadw(emb, (size_t)tok * (2 * F_) + F_ + f, isbf);
}

// generic dtype-cast copy: dst[i] = (bf16)src[soff + i]
__global__ __launch_bounds__(256)
void cvt_kernel(bf16* __restrict__ dst, const void* __restrict__ src,
                size_t soff, int n, const int* __restrict__ flag)
{
    const int isbf = flag[0];
    int i = blockIdx.x * 256 + threadIdx.x;
    if (i < n) dst[i] = __float2bfloat16(loadw(src, soff + i, isbf));
}

// zero the 6 pad rows of all P vbt slices (re-poisoned every call)
__global__ __launch_bounds__(256)
void zeropad_kernel(bf16* __restrict__ vbt, int nslice)
{
    int i = blockIdx.x * 256 + threadIdx.x;
    if (i < nslice * 6 * I_) {
        int z = i / (6 * I_), off = i % (6 * I_);
        vbt[(size_t)z * VR_ * I_ + off] = __float2bfloat16(0.0f);
    }
}

// Inputs t are PRE-MISHED by the gemm epilogue.
// v[i,s] = cumsum_s(t[i,s])/(s+1) * t[I+i,s] + t[2I+i,s]; bf16 output.
// grid (I_, P): blockIdx.y = z scratch slice
__global__ __launch_bounds__(256)
void scan_kernel(bf16* __restrict__ vout, const float* __restrict__ t)
{
    const int z = blockIdx.y;
    const int i = blockIdx.x;
    t    += (size_t)z * I3_ * S_;
    vout += (size_t)z * I_ * S_;
    const float* dp  = t + (size_t)i * S_;
    const float* scp = dp + (size_t)I_ * S_;
    const float* shp = dp + (size_t)(2 * I_) * S_;
    bf16* op = vout + (size_t)i * S_;
    const int tid = threadIdx.x;
    const int base = tid * 16;

    float md[16];
    float lsum = 0.f;
    #pragma unroll
    for (int q = 0; q < 4; ++q) {
        float4 dv = *(const float4*)(dp + base + q * 4);
        #pragma unroll
        for (int j = 0; j < 4; ++j) {
            float m = (&dv.x)[j];
            md[q * 4 + j] = m;
            lsum += m;
        }
    }
    float ssum = lsum;
    #pragma unroll
    for (int off = 1; off < 64; off <<= 1) {
        float nv = __shfl_up(ssum, off, 64);
        if ((tid & 63) >= off) ssum += nv;
    }
    __shared__ float wtot[4];
    const int wid = tid >> 6, lane = tid & 63;
    if (lane == 63) wtot[wid] = ssum;
    __syncthreads();
    float excl = ssum - lsum;
    #pragma unroll
    for (int wq = 0; wq < 3; ++wq)
        if (wq < wid) excl += wtot[wq];

    float run = excl;
    bf16x8 o0v, o1v;
    #pragma unroll
    for (int q = 0; q < 4; ++q) {
        float4 scv = *(const float4*)(scp + base + q * 4);
        float4 shv = *(const float4*)(shp + base + q * 4);
        #pragma unroll
        for (int j = 0; j < 4; ++j) {
            run += md[q * 4 + j];
            float sdiv = (float)(base + q * 4 + j + 1);
            float ov = run / sdiv * (&scv.x)[j] + (&shv.x)[j];
            if (q < 2) o0v[q * 4 + j] = tobf(ov);
            else       o1v[(q - 2) * 4 + j] = tobf(ov);
        }
    }
    *(bf16x8*)(void*)(op + base) = o0v;
    *(bf16x8*)(void*)(op + base + 8) = o1v;
}

// w1 [o][c][k] (k innermost) -> wexp [o][k*512+c] bf16 (flattened-K A matrix)
__global__ __launch_bounds__(256)
void wexp_kernel(bf16* __restrict__ wexp, const void* __restrict__ w1,
                 size_t woff, const int* __restrict__ flag)
{
    const int isbf = flag[0];
    int idx = blockIdx.x * 256 + threadIdx.x;      // over 1536*512
    int c = idx & 511, o = idx >> 9;
    const size_t base = woff + ((size_t)o * 512 + c) * 7;
    float vals[7];
    #pragma unroll
    for (int k = 0; k < 7; ++k) vals[k] = loadw(w1, base + k, isbf);
    #pragma unroll
    for (int k = 0; k < 7; ++k)
        wexp[(size_t)o * KE_ + (k << 9) + c] = __float2bfloat16(vals[k]);
}

// src fp32 [C][S_] (+z*szstr) -> dst bf16 [S_][C] (+z*dzstr); 64x64 LDS tile
__global__ __launch_bounds__(256)
void trans_kernel(bf16* __restrict__ dst, size_t dzstr,
                  const float* __restrict__ src, size_t szstr, int C)
{
    __shared__ __align__(16) bf16 lt[64][72];
    const int z = blockIdx.z;
    dst += (size_t)z * dzstr;
    src += (size_t)z * szstr;
    const int tid = threadIdx.x;
    const int s0 = blockIdx.x * 64;
    const int c0 = blockIdx.y * 64;
    #pragma unroll
    for (int p = 0; p < 4; ++p) {
        int c = p * 16 + (tid >> 4);
        int sc = (tid & 15) * 4;
        float4 f = *(const float4*)(src + (size_t)(c0 + c) * S_ + s0 + sc);
        #pragma unroll
        for (int j = 0; j < 4; ++j)
            lt[sc + j][c] = __float2bfloat16((&f.x)[j]);
    }
    __syncthreads();
    #pragma unroll
    for (int p = 0; p < 2; ++p) {
        int ch = p * 256 + tid;
        int r = ch >> 3, g = ch & 7;
        *(bf16x8*)(dst + (size_t)(s0 + r) * C + c0 + g * 8) =
            *(const bf16x8*)&lt[r][g * 8];
    }
}

// src bf16 [C][S_] (+z*szstr) -> dst bf16 [S_][C] (+z*dzstr); 64x64 LDS tile
__global__ __launch_bounds__(256)
void transb_kernel(bf16* __restrict__ dst, size_t dzstr,
                   const bf16* __restrict__ src, size_t szstr, int C)
{
    __shared__ __align__(16) bf16 lt[64][72];
    const int z = blockIdx.z;
    dst += (size_t)z * dzstr;
    src += (size_t)z * szstr;
    const int tid = threadIdx.x;
    const int s0 = blockIdx.x * 64;
    const int c0 = blockIdx.y * 64;
    #pragma unroll
    for (int p = 0; p < 2; ++p) {
        int c = p * 32 + (tid >> 3);
        int sc = (tid & 7) * 8;
        bf16x8 v = *(const bf16x8*)(src + (size_t)(c0 + c) * S_ + s0 + sc);
        #pragma unroll
        for (int j = 0; j < 8; ++j)
            *(__bf16*)&lt[sc + j][c] = v[j];
    }
    __syncthreads();
    #pragma unroll
    for (int p = 0; p < 2; ++p) {
        int ch = p * 256 + tid;
        int r = ch >> 3, g = ch & 7;
        *(bf16x8*)(dst + (size_t)(s0 + r) * C + c0 + g * 8) =
            *(const bf16x8*)&lt[r][g * 8];
    }
}

// ---------------------------------------------------------------------------
// 192(o) x 256(s) tile GEMM; A TRI-buffered (72 KB) + B DOUBLE-buffered
// (64 KB) LDS = 136 KiB; 4 phases per K-tile (BK=64); COUNTED vmcnt (T4).
// Grid = 16 x 8 x P = 512 (P=4): exact 2 rounds over 256 CUs.
// 8 waves (2M x 4N); per-wave 96o x 64s; acc[6][4] (96 acc regs).
// Per tile t (abuf ca=t%3, bbuf cb=t&1):
//   ph1: 7 reads + stage B(t+1) half0 (2 loads -> bbuf cb^1)
//   ph2: 3 reads + stage B(t+1) half1 (2 loads)
//   ph3: 7 reads + stage A(t+2) (3 loads -> abuf (t+2)%3)
//   ph4: 3 reads; MFMA; then vmcnt(3) + barrier.
// Issue order per tile = B(t+1) then A(t+2), so at tile end the 7 OLDEST
// in-flight loads are exactly A(t+1)+B(t+1): vmcnt(3) drains precisely them
// and leaves A(t+2)'s 3 loads flying across the barrier (never drain to 0 —
// m218's counted-vs-drain0 lever, R5's vmcnt(0)-per-tile was the violation).
// WAR: B restage (t ph1) is >=1 barrier after bbuf^1's last read (t-1 ph3);
//      A restage (t ph3) is >=3 barriers after abuf (t+2)%3's last read
//      (t-1 ph4; same buffer since (t-1)%3 == (t+2)%3).
// RAW: prologue WVM(3) lands tile0; steady-state arithmetic above; tails:
//      t+2>=nKt -> no A stage -> vmcnt(0) at that tile's end.
// domish: fused mish on the fp32 result (feeds scan_kernel).
// ---------------------------------------------------------------------------
__global__ __launch_bounds__(512, 1)
void gemm192_kernel(float* __restrict__ out, size_t ozstr,
                    const bf16* __restrict__ Aw, int lda,
                    const bf16* __restrict__ Bm, size_t bzstr, int ldb,
                    int Kdim, int conv, int domish)
{
    __shared__ __align__(16) bf16 la[3][192][64];   // 72 KiB (tri)
    __shared__ __align__(16) bf16 lb[2][256][64];   // 64 KiB (double)
    const int tid = threadIdx.x;
    const int s0 = blockIdx.x * 256;
    const int o0 = blockIdx.y * 192;
    const int z  = blockIdx.z;
    out += (size_t)z * ozstr;
    Bm  += (size_t)z * bzstr;
    const int wv = tid >> 6, lane = tid & 63;
    const int wr = wv >> 2, wc = wv & 3;            // 2(M) x 4(N) waves
    const int l16 = lane & 15, q = lane >> 4;
    const int srow = lane >> 3;                     // staging row within 8-row strip
    const int schunk = (lane & 7) ^ srow;           // pre-swizzled source chunk
    const int nKt = Kdim >> 6;

    f32x4 acc[6][4];
    #pragma unroll
    for (int i = 0; i < 6; ++i)
        #pragma unroll
        for (int j = 0; j < 4; ++j)
            #pragma unroll
            for (int r = 0; r < 4; ++r) acc[i][j][r] = 0.f;

#define STAGE_A3(buf, kt) do {                                                \
    const bf16* gpA_ = Aw + (size_t)(o0 + wv * 8 + srow) * lda                \
                          + ((kt) << 6) + (schunk << 3);                      \
    __builtin_amdgcn_global_load_lds(GLB_PTR(gpA_),                           \
        LDS_PTR(&la[buf][wv * 8][0]), 16, 0, 0);                              \
    __builtin_amdgcn_global_load_lds(GLB_PTR(gpA_ + (size_t)64 * lda),        \
        LDS_PTR(&la[buf][64 + wv * 8][0]), 16, 0, 0);                         \
    __builtin_amdgcn_global_load_lds(GLB_PTR(gpA_ + (size_t)128 * lda),       \
        LDS_PTR(&la[buf][128 + wv * 8][0]), 16, 0, 0);                        \
} while (0)

#define STAGE_BL(buf, l, ro, bk) do {                                         \
    const bf16* gpB_ = Bm + (size_t)(s0 + (l) * 64 + wv * 8 + srow + (ro)) * ldb \
                          + (bk) + (schunk << 3);                             \
    __builtin_amdgcn_global_load_lds(GLB_PTR(gpB_),                           \
        LDS_PTR(&lb[buf][(l) * 64 + wv * 8][0]), 16, 0, 0);                   \
} while (0)

#define LDAF3(buf, kk, ih) do {                                               \
    _Pragma("unroll") for (int i2 = 0; i2 < 3; ++i2) {                        \
        int r_ = wr * 96 + (ih) * 48 + i2 * 16 + l16;                         \
        af[i2] = *(const bf16x8*)&la[buf][r_][(((kk) * 4 + q) ^ (r_ & 7)) << 3]; \
    }                                                                         \
} while (0)

#define LDBF4(buf, kk) do {                                                   \
    _Pragma("unroll") for (int j2 = 0; j2 < 4; ++j2) {                        \
        int r_ = wc * 64 + j2 * 16 + l16;                                     \
        bfr[j2] = *(const bf16x8*)&lb[buf][r_][(((kk) * 4 + q) ^ (r_ & 7)) << 3]; \
    }                                                                         \
} while (0)

#define MFMA12(ih) do {                                                       \
    __builtin_amdgcn_s_setprio(1);                                            \
    _Pragma("unroll") for (int i2 = 0; i2 < 3; ++i2)                          \
    _Pragma("unroll") for (int j2 = 0; j2 < 4; ++j2)                          \
        acc[(ih) * 3 + i2][j2] = __builtin_amdgcn_mfma_f32_16x16x32_bf16(     \
            af[i2], bfr[j2], acc[(ih) * 3 + i2][j2], 0, 0, 0);                \
    __builtin_amdgcn_s_setprio(0);                                            \
} while (0)

#define BARR()  __builtin_amdgcn_s_barrier()
#define WLGKM() asm volatile("s_waitcnt lgkmcnt(0)" ::: "memory")
#define WVM3()  asm volatile("s_waitcnt vmcnt(3)" ::: "memory")
#define WVM0()  asm volatile("s_waitcnt vmcnt(0)" ::: "memory")

    // prologue: B(0)+A(0) -> buffers 0, then A(1) -> abuf1.
    // vmcnt(3): drains the 7 oldest (= tile0), leaves A(1)'s 3 flying.
    STAGE_BL(0, 0, 0, 0); STAGE_BL(0, 1, 0, 0);
    STAGE_BL(0, 2, 0, 0); STAGE_BL(0, 3, 0, 0);
    STAGE_A3(0, 0);
    STAGE_A3(1, 1);                               // nKt >= 4 for all uses
    WVM3();
    BARR();

    bf16x8 af[3], bfr[4];
    int ca = 0;
    for (int t = 0; t < nKt; ++t) {
        const int cb = t & 1, nb = cb ^ 1;
        int na = ca + 2; if (na >= 3) na -= 3;    // (t+2)%3
        const bool stB = (t + 1) < nKt;
        const bool stA = (t + 2) < nKt;
        int ro1 = 0, bk1 = (t + 1) << 6;
        if (conv) { ro1 = bk1 >> 9; bk1 &= 511; }
        // ---- phase 1 (kk0, ihalf0): 7 reads; stage B(t+1) half0
        LDAF3(ca, 0, 0); LDBF4(cb, 0);
        if (stB) { STAGE_BL(nb, 0, ro1, bk1); STAGE_BL(nb, 1, ro1, bk1); }
        BARR(); WLGKM();
        MFMA12(0);
        BARR();
        // ---- phase 2 (kk0, ihalf1): 3 reads; stage B(t+1) half1
        LDAF3(ca, 0, 1);
        if (stB) { STAGE_BL(nb, 2, ro1, bk1); STAGE_BL(nb, 3, ro1, bk1); }
        BARR(); WLGKM();
        MFMA12(1);
        BARR();
        // ---- phase 3 (kk1, ihalf0): 7 reads; stage A(t+2)
        LDAF3(ca, 1, 0); LDBF4(cb, 1);
        if (stA) STAGE_A3(na, t + 2);
        BARR(); WLGKM();
        MFMA12(0);
        BARR();
        // ---- phase 4 (kk1, ihalf1): 3 reads; counted wait; publish
        LDAF3(ca, 1, 1);
        BARR(); WLGKM();
        MFMA12(1);
        if (stA) { WVM3(); } else { WVM0(); }     // drain A(t+1)+B(t+1) only
        BARR();
        ca += 1; if (ca >= 3) ca = 0;
    }

    // C/D: col(lane&15)=s, row(q*4+reg)=o   [verified convention]
    #pragma unroll
    for (int i = 0; i < 6; ++i)
        #pragma unroll
        for (int j = 0; j < 4; ++j) {
            int sg = s0 + wc * 64 + j * 16 + l16;
            #pragma unroll
            for (int r = 0; r < 4; ++r) {
                int og = o0 + wr * 96 + i * 16 + q * 4 + r;
                float v = acc[i][j][r];
                if (domish) v = mishf(v);
                out[(size_t)og * S_ + sg] = v;
            }
        }
#undef STAGE_A3
#undef STAGE_BL
#undef LDAF3
#undef LDBF4
#undef MFMA12
#undef BARR
#undef WLGKM
#undef WVM3
#undef WVM0
}

// 128x128 GEMM (m97 structure) kept for the small w2 conv (M=256) + accumulate.
__global__ __launch_bounds__(256)
void gemm128_kernel(float* __restrict__ out, size_t ozstr,
                    const bf16* __restrict__ Aw, int lda,
                    const bf16* __restrict__ Bm, size_t bzstr, int ldb,
                    int Kdim, int conv, int addres)
{
    __shared__ __align__(16) bf16 la[128][64];
    __shared__ __align__(16) bf16 lb[128][64];
    const int tid = threadIdx.x;
    const int s0 = blockIdx.x * 128;
    const int o0 = blockIdx.y * 128;
    const int z  = blockIdx.z;
    out += (size_t)z * ozstr;
    Bm  += (size_t)z * bzstr;
    const int wv = tid >> 6, lane = tid & 63;
    const int wo = wv & 1, wsv = wv >> 1;
    const int l16 = lane & 15, q = lane >> 4;
    const int lrow = lane >> 3, lslot = lane & 7;

    f32x4 acc[4][4];
    #pragma unroll
    for (int i = 0; i < 4; ++i)
        #pragma unroll
        for (int j = 0; j < 4; ++j)
            #pragma unroll
            for (int r = 0; r < 4; ++r) acc[i][j][r] = 0.f;

    for (int k0 = 0; k0 < Kdim; k0 += 64) {
        int roff = 0, bk = k0;
        if (conv) { roff = k0 >> 9; bk = k0 & 511; }
        __syncthreads();
        #pragma unroll
        for (int t = 0; t < 4; ++t) {
            int rbase = wv * 32 + t * 8;
            int row = rbase + lrow;
            int chunk = lslot ^ (row & 7);
            __builtin_amdgcn_global_load_lds(
                GLB_PTR(Aw + (size_t)(o0 + row) * lda + k0 + chunk * 8),
                LDS_PTR(&la[rbase][0]), 16, 0, 0);
        }
        #pragma unroll
        for (int t = 0; t < 4; ++t) {
            int rbase = wv * 32 + t * 8;
            int row = rbase + lrow;
            int chunk = lslot ^ (row & 7);
            __builtin_amdgcn_global_load_lds(
                GLB_PTR(Bm + (size_t)(s0 + row + roff) * ldb + bk + chunk * 8),
                LDS_PTR(&lb[rbase][0]), 16, 0, 0);
        }
        __syncthreads();
        #pragma unroll
        for (int kk = 0; kk < 2; ++kk) {
            bf16x8 af[4], bfr[4];
            #pragma unroll
            for (int i = 0; i < 4; ++i) {
                int r = wo * 64 + i * 16 + l16;
                int c = kk * 4 + q;
                af[i] = *(const bf16x8*)&la[r][(c ^ (r & 7)) * 8];
            }
            #pragma unroll
            for (int j = 0; j < 4; ++j) {
                int r = wsv * 64 + j * 16 + l16;
                int c = kk * 4 + q;
                bfr[j] = *(const bf16x8*)&lb[r][(c ^ (r & 7)) * 8];
            }
            #pragma unroll
            for (int i = 0; i < 4; ++i)
                #pragma unroll
                for (int j = 0; j < 4; ++j)
                    acc[i][j] = __builtin_amdgcn_mfma_f32_16x16x32_bf16(
                        af[i], bfr[j], acc[i][j], 0, 0, 0);
        }
    }
    #pragma unroll
    for (int i = 0; i < 4; ++i)
        #pragma unroll
        for (int j = 0; j < 4; ++j) {
            int sg = s0 + wsv * 64 + j * 16 + l16;
            #pragma unroll
            for (int r = 0; r < 4; ++r) {
                int og = o0 + wo * 64 + i * 16 + q * 4 + r;
                float v = acc[i][j][r];
                if (addres) v += out[(size_t)og * S_ + sg];
                out[(size_t)og * S_ + sg] = v;
            }
        }
}

__global__ __launch_bounds__(256)
void final_kernel(void* __restrict__ out, const float* __restrict__ x0,
                  const float* __restrict__ x1, const void* __restrict__ ow,
                  const void* __restrict__ ob, const int* __restrict__ flag)
{
    __shared__ float wl[16][68];
    __shared__ float xl[16][68];
    const int isbf = flag[0];
    const int tid = threadIdx.x;
    const int tx = tid & 15, ty = tid >> 4;
    const int s0 = blockIdx.x * 64;
    const int o0 = blockIdx.y * 64;
    const int b  = blockIdx.z;
    float acc[4][4] = {};
    for (int c0 = 0; c0 < 2 * F_; c0 += 16) {
        if (isbf) {
            #pragma unroll
            for (int e = tid; e < 1024; e += 256) {
                int k = e & 15, o = e >> 4;
                wl[k][o] = __bfloat162float(((const bf16*)ow)[(size_t)(o0 + o) * (2 * F_) + (c0 + k)]);
            }
        } else {
            #pragma unroll
            for (int e = tid; e < 1024; e += 256) {
                int k = e & 15, o = e >> 4;
                wl[k][o] = ((const float*)ow)[(size_t)(o0 + o) * (2 * F_) + (c0 + k)];
            }
        }
        {
            int r = tid >> 4;
            int qq = (tid & 15) * 4;
            int cr = c0 + r;
            const float* src = (cr < F_) ? (x0 + ((size_t)b * F_ + cr) * S_)
                                         : (x1 + ((size_t)b * F_ + (cr - F_)) * S_);
            *(float4*)&xl[r][qq] = *(const float4*)(src + s0 + qq);
        }
        __syncthreads();
        #pragma unroll
        for (int k = 0; k < 16; ++k) {
            float4 av = *(const float4*)&wl[k][ty * 4];
            float4 bv = *(const float4*)&xl[k][tx * 4];
            #pragma unroll
            for (int i = 0; i < 4; ++i)
                #pragma unroll
                for (int j = 0; j < 4; ++j)
                    acc[i][j] += (&av.x)[i] * (&bv.x)[j];
        }
        __syncthreads();
    }
    #pragma unroll
    for (int i = 0; i < 4; ++i) {
        int o = o0 + ty * 4 + i;
        float bias = loadw(ob, o, isbf);
        size_t outoff = ((size_t)b * V_ + o) * S_ + s0 + tx * 4;
        if (isbf) {
            bf16* po = (bf16*)out + outoff;
            #pragma unroll
            for (int j = 0; j < 4; ++j)
                po[j] = __float2bfloat16(acc[i][j] + bias);
        } else {
            float* po = (float*)out + outoff;
            *(float4*)po = make_float4(acc[i][0] + bias, acc[i][1] + bias,
                                       acc[i][2] + bias, acc[i][3] + bias);
        }
    }
}

extern "C" void kernel_launch(void* const* d_in, const int* in_sizes, int n_in,
                              void* d_out, int out_size, void* d_ws, size_t ws_size,
                              hipStream_t stream)
{
    const int*  inp  = (const int*)d_in[0];
    const void* emb  = d_in[1];
    const void* w0   = d_in[2];
    const void* w1   = d_in[3];
    const void* w2   = d_in[4];
    const void* outw = d_in[5];
    const void* outb = d_in[6];

    const size_t NX = (size_t)B_ * F_ * S_;
    const size_t NT = (size_t)I3_ * S_;
    const size_t NV = (size_t)I_ * S_;
    const size_t VSTR = (size_t)VR_ * I_;     // vbt z-stride (elements)

    // P = batch slices processed per dispatch; pick largest fitting ws_size.
    auto need = [&](int p) -> size_t {
        return 256 + 8 * NX + (size_t)4 * p * NT + (size_t)2 * p * NV
             + 2 * ((size_t)I3_ * KE_ + (size_t)p * VSTR + (size_t)p * S_ * F_
                    + (size_t)I3_ * F_ + (size_t)F_ * I_);
    };
    int P = 2;
    if (ws_size >= need(8)) P = 8;
    else if (ws_size >= need(4)) P = 4;

    int*   flag = (int*)d_ws;
    float* A  = (float*)d_ws + 64;
    float* Bb = A + NX;
    float* T  = Bb + NX;                       // P slices, fp32 (pre-mished)
    bf16*  Vv = (bf16*)(T + (size_t)P * NT);   // P slices, bf16
    bf16*  wexp = Vv + (size_t)P * NV;
    bf16*  vbt  = wexp + (size_t)I3_ * KE_;    // P slices, 6-row zero pad each
    bf16*  xbt  = vbt + (size_t)P * VSTR;      // P slices
    bf16*  wb0  = xbt + (size_t)P * S_ * F_;
    bf16*  wb2  = wb0 + (size_t)I3_ * F_;

    detect_kernel<<<1, 256, 0, stream>>>(flag, (const unsigned short*)emb);
    embed_kernel<<<dim3((unsigned)(NX / 256)), 256, 0, stream>>>(A, Bb, inp, emb, flag);
    zeropad_kernel<<<dim3((P * 6 * I_ + 255) / 256), 256, 0, stream>>>(vbt, P);

    int swap = 0;
    for (int d = 0; d < D_; ++d) {
        wexp_kernel<<<dim3(I3_ * I_ / 256), 256, 0, stream>>>(
            wexp, w1, (size_t)d * I3_ * I_ * K_, flag);
        cvt_kernel<<<dim3(I3_ * F_ / 256), 256, 0, stream>>>(
            wb0, w0, (size_t)d * I3_ * F_, I3_ * F_, flag);
        cvt_kernel<<<dim3(F_ * I_ / 256), 256, 0, stream>>>(
            wb2, w2, (size_t)d * F_ * I_, F_ * I_, flag);
        for (int bp = 0; bp < B_ / P; ++bp) {
            float* x0 = (swap ? Bb : A) + (size_t)(P * bp) * F_ * S_;
            float* x1 = (swap ? A : Bb) + (size_t)(P * bp) * F_ * S_;
            // xbt[z] = x1(b)^T bf16
            trans_kernel<<<dim3(S_ / 64, F_ / 64, P), 256, 0, stream>>>(
                xbt, (size_t)S_ * F_, x1, (size_t)F_ * S_, F_);
            // T[z] = mish(wb0 @ xbt[z])   (192x256-tile, grid 16*8*P = 512)
            gemm192_kernel<<<dim3(S_ / 256, I3_ / 192, P), 512, 0, stream>>>(
                T, NT, wb0, F_, xbt, (size_t)S_ * F_, F_, F_, 0, 1);
            scan_kernel<<<dim3(I_, P), 256, 0, stream>>>(Vv, T);
            // vbt[z] rows 6.. = Vv[z]^T (pad rows 0..5 stay zero)
            transb_kernel<<<dim3(S_ / 64, I_ / 64, P), 256, 0, stream>>>(
                vbt + 6 * I_, VSTR, Vv, NV, I_);
            // T[z] = mish(causal conv as flattened-K GEMM)
            gemm192_kernel<<<dim3(S_ / 256, I3_ / 192, P), 512, 0, stream>>>(
                T, NT, wexp, KE_, vbt, VSTR, I_, KE_, 1, 1);
            scan_kernel<<<dim3(I_, P), 256, 0, stream>>>(Vv, T);
            transb_kernel<<<dim3(S_ / 64, I_ / 64, P), 256, 0, stream>>>(
                vbt + 6 * I_, VSTR, Vv, NV, I_);
            // x0(b) += wb2 @ v[z]   (small M=256: keep 128-tile kernel, grid 256)
            gemm128_kernel<<<dim3(S_ / 128, F_ / 128, P), 256, 0, stream>>>(
                x0, (size_t)F_ * S_, wb2, I_, vbt + 6 * I_, VSTR, I_, I_, 0, 1);
        }
        swap ^= 1;
    }
    final_kernel<<<dim3(S_ / 64, V_ / 64, B_), 256, 0, stream>>>(d_out, A, Bb, outw, outb, flag);
    (void)in_sizes; (void)n_in; (void)out_size;
}

// Round 7
// 2650.051 us; speedup vs baseline: 1.0964x; 1.0964x over previous
//
#include <hip/hip_runtime.h>
#include <hip/hip_bf16.h>

#define B_ 8
#define S_ 4096
#define F_ 256
#define I_ 512
#define D_ 4
#define K_ 7
#define V_ 256
#define I3_ 1536
#define KE_ 3584           // 7*512 flattened causal-conv K
#define VR_ (S_ + 8)       // vbt rows: 6 zero-pad + 4096 + 2 slack

using bf16 = __hip_bfloat16;
typedef __bf16 bf16x8 __attribute__((ext_vector_type(8)));
typedef float  f32x4  __attribute__((ext_vector_type(4)));

#define LDS_PTR(p) ((__attribute__((address_space(3))) void*)(p))
#define GLB_PTR(p) ((const __attribute__((address_space(1))) void*)(p))

// mish(x) = x*tanh(softplus(x)) = x*(u^2+2u)/(u^2+2u+2), u=e^x (exact closed form).
__device__ __forceinline__ float mishf(float x) {
    float u = expf(fminf(x, 30.0f));
    float t = u * (u + 2.0f);
    return x * (t / (t + 2.0f));
}

__device__ __forceinline__ float loadw(const void* p, size_t i, int isbf) {
    return isbf ? __bfloat162float(((const bf16*)p)[i]) : ((const float*)p)[i];
}

__device__ __forceinline__ __bf16 tobf(float x) {
    bf16 h = __float2bfloat16(x);
    return *(__bf16*)&h;
}

// bf16 buffers of small weights never show bf16-exponent>=132 (|x|>=32);
// fp32 buffers read as uint16 do (random mantissa bits in low halves).
__global__ __launch_bounds__(256)
void detect_kernel(int* __restrict__ flag, const unsigned short* __restrict__ p)
{
    __shared__ int sh[256];
    int cnt = 0;
    for (int j = threadIdx.x; j < 16384; j += 256) {
        unsigned int e = (p[j] >> 7) & 0xffu;
        if (e >= 132u) cnt++;
    }
    sh[threadIdx.x] = cnt;
    __syncthreads();
    for (int s = 128; s > 0; s >>= 1) {
        if ((int)threadIdx.x < s) sh[threadIdx.x] += sh[threadIdx.x + s];
        __syncthreads();
    }
    if (threadIdx.x == 0) flag[0] = (sh[0] == 0) ? 1 : 0;   // 1 => bf16 inputs
}

__global__ __launch_bounds__(256)
void embed_kernel(float* __restrict__ x0, float* __restrict__ x1,
                  const int* __restrict__ inp, const void* __restrict__ emb,
                  const int* __restrict__ flag)
{
    const int isbf = flag[0];
    size_t idx = (size_t)blockIdx.x * 256 + threadIdx.x;   // over B*F*S
    int s = (int)(idx % S_);
    int f = (int)((idx / S_) % F_);
    int b = (int)(idx / ((size_t)S_ * F_));
    int tok = inp[b * S_ + s];
    x0[idx] = loadw(emb, (size_t)tok * (2 * F_) + f, isbf);
    x1[idx] = loadw(emb, (size_t)tok * (2 * F_) + F_ + f, isbf);
}

// generic dtype-cast copy: dst[i] = (bf16)src[soff + i]
__global__ __launch_bounds__(256)
void cvt_kernel(bf16* __restrict__ dst, const void* __restrict__ src,
                size_t soff, int n, const int* __restrict__ flag)
{
    const int isbf = flag[0];
    int i = blockIdx.x * 256 + threadIdx.x;
    if (i < n) dst[i] = __float2bfloat16(loadw(src, soff + i, isbf));
}

// zero the 6 pad rows of all P vbt slices (re-poisoned every call)
__global__ __launch_bounds__(256)
void zeropad_kernel(bf16* __restrict__ vbt, int nslice)
{
    int i = blockIdx.x * 256 + threadIdx.x;
    if (i < nslice * 6 * I_) {
        int z = i / (6 * I_), off = i % (6 * I_);
        vbt[(size_t)z * VR_ * I_ + off] = __float2bfloat16(0.0f);
    }
}

// Inputs t are PRE-MISHED by the gemm epilogue.
// v[i,s] = cumsum_s(t[i,s])/(s+1) * t[I+i,s] + t[2I+i,s]; bf16 output.
// grid (I_, P): blockIdx.y = z scratch slice
__global__ __launch_bounds__(256)
void scan_kernel(bf16* __restrict__ vout, const float* __restrict__ t)
{
    const int z = blockIdx.y;
    const int i = blockIdx.x;
    t    += (size_t)z * I3_ * S_;
    vout += (size_t)z * I_ * S_;
    const float* dp  = t + (size_t)i * S_;
    const float* scp = dp + (size_t)I_ * S_;
    const float* shp = dp + (size_t)(2 * I_) * S_;
    bf16* op = vout + (size_t)i * S_;
    const int tid = threadIdx.x;
    const int base = tid * 16;

    float md[16];
    float lsum = 0.f;
    #pragma unroll
    for (int q = 0; q < 4; ++q) {
        float4 dv = *(const float4*)(dp + base + q * 4);
        #pragma unroll
        for (int j = 0; j < 4; ++j) {
            float m = (&dv.x)[j];
            md[q * 4 + j] = m;
            lsum += m;
        }
    }
    float ssum = lsum;
    #pragma unroll
    for (int off = 1; off < 64; off <<= 1) {
        float nv = __shfl_up(ssum, off, 64);
        if ((tid & 63) >= off) ssum += nv;
    }
    __shared__ float wtot[4];
    const int wid = tid >> 6, lane = tid & 63;
    if (lane == 63) wtot[wid] = ssum;
    __syncthreads();
    float excl = ssum - lsum;
    #pragma unroll
    for (int wq = 0; wq < 3; ++wq)
        if (wq < wid) excl += wtot[wq];

    float run = excl;
    bf16x8 o0v, o1v;
    #pragma unroll
    for (int q = 0; q < 4; ++q) {
        float4 scv = *(const float4*)(scp + base + q * 4);
        float4 shv = *(const float4*)(shp + base + q * 4);
        #pragma unroll
        for (int j = 0; j < 4; ++j) {
            run += md[q * 4 + j];
            float sdiv = (float)(base + q * 4 + j + 1);
            float ov = run / sdiv * (&scv.x)[j] + (&shv.x)[j];
            if (q < 2) o0v[q * 4 + j] = tobf(ov);
            else       o1v[(q - 2) * 4 + j] = tobf(ov);
        }
    }
    *(bf16x8*)(void*)(op + base) = o0v;
    *(bf16x8*)(void*)(op + base + 8) = o1v;
}

// w1 [o][c][k] (k innermost) -> wexp [o][k*512+c] bf16 (flattened-K A matrix)
__global__ __launch_bounds__(256)
void wexp_kernel(bf16* __restrict__ wexp, const void* __restrict__ w1,
                 size_t woff, const int* __restrict__ flag)
{
    const int isbf = flag[0];
    int idx = blockIdx.x * 256 + threadIdx.x;      // over 1536*512
    int c = idx & 511, o = idx >> 9;
    const size_t base = woff + ((size_t)o * 512 + c) * 7;
    float vals[7];
    #pragma unroll
    for (int k = 0; k < 7; ++k) vals[k] = loadw(w1, base + k, isbf);
    #pragma unroll
    for (int k = 0; k < 7; ++k)
        wexp[(size_t)o * KE_ + (k << 9) + c] = __float2bfloat16(vals[k]);
}

// src fp32 [C][S_] (+z*szstr) -> dst bf16 [S_][C] (+z*dzstr); 64x64 LDS tile
__global__ __launch_bounds__(256)
void trans_kernel(bf16* __restrict__ dst, size_t dzstr,
                  const float* __restrict__ src, size_t szstr, int C)
{
    __shared__ __align__(16) bf16 lt[64][72];
    const int z = blockIdx.z;
    dst += (size_t)z * dzstr;
    src += (size_t)z * szstr;
    const int tid = threadIdx.x;
    const int s0 = blockIdx.x * 64;
    const int c0 = blockIdx.y * 64;
    #pragma unroll
    for (int p = 0; p < 4; ++p) {
        int c = p * 16 + (tid >> 4);
        int sc = (tid & 15) * 4;
        float4 f = *(const float4*)(src + (size_t)(c0 + c) * S_ + s0 + sc);
        #pragma unroll
        for (int j = 0; j < 4; ++j)
            lt[sc + j][c] = __float2bfloat16((&f.x)[j]);
    }
    __syncthreads();
    #pragma unroll
    for (int p = 0; p < 2; ++p) {
        int ch = p * 256 + tid;
        int r = ch >> 3, g = ch & 7;
        *(bf16x8*)(dst + (size_t)(s0 + r) * C + c0 + g * 8) =
            *(const bf16x8*)&lt[r][g * 8];
    }
}

// src bf16 [C][S_] (+z*szstr) -> dst bf16 [S_][C] (+z*dzstr); 64x64 LDS tile
__global__ __launch_bounds__(256)
void transb_kernel(bf16* __restrict__ dst, size_t dzstr,
                   const bf16* __restrict__ src, size_t szstr, int C)
{
    __shared__ __align__(16) bf16 lt[64][72];
    const int z = blockIdx.z;
    dst += (size_t)z * dzstr;
    src += (size_t)z * szstr;
    const int tid = threadIdx.x;
    const int s0 = blockIdx.x * 64;
    const int c0 = blockIdx.y * 64;
    #pragma unroll
    for (int p = 0; p < 2; ++p) {
        int c = p * 32 + (tid >> 3);
        int sc = (tid & 7) * 8;
        bf16x8 v = *(const bf16x8*)(src + (size_t)(c0 + c) * S_ + s0 + sc);
        #pragma unroll
        for (int j = 0; j < 8; ++j)
            *(__bf16*)&lt[sc + j][c] = v[j];
    }
    __syncthreads();
    #pragma unroll
    for (int p = 0; p < 2; ++p) {
        int ch = p * 256 + tid;
        int r = ch >> 3, g = ch & 7;
        *(bf16x8*)(dst + (size_t)(s0 + r) * C + c0 + g * 8) =
            *(const bf16x8*)&lt[r][g * 8];
    }
}

// ---------------------------------------------------------------------------
// 192(o) x 256(s) tile GEMM, double-buffered LDS (112 KiB), TWO phases per
// K-tile (BK=64) => 3 barriers/K-tile (was 8 in the 4-phase variant).
// Grid = 16 x 8 x P = 512 (P=4): exact 2 rounds over 256 CUs.
// 8 waves (2M x 4N); per-wave 96o x 64s; acc[6][4].
// Phase = {10 ds_read (6 A + 4 B) || stage || BARR || lgkmcnt(0) ||
//          setprio 24xMFMA} — pre-MFMA rendezvous KEPT (R4/m196 lesson:
// dropping it collapses util); only the post-MFMA barriers are removed.
// Tile t (buf c=t&1): ph1 stages A(t+1) (3 loads -> buf n), ph2 stages
// B(t+1) (4 loads) then vmcnt(0)+BARR publishes tile t+1.
// WAR: buf n's restage (t ph1/ph2) is >=1 barrier (t-1 end-barrier) after
//      buf n's last read (t-1 ph2). Read-read overlap across phases is safe.
// RAW: per-wave vmcnt(0) + end-barrier -> all waves' stages landed before
//      any tile-t+1 read.
// domish: fused mish on the fp32 result (feeds scan_kernel).
// ---------------------------------------------------------------------------
__global__ __launch_bounds__(512, 1)
void gemm192_kernel(float* __restrict__ out, size_t ozstr,
                    const bf16* __restrict__ Aw, int lda,
                    const bf16* __restrict__ Bm, size_t bzstr, int ldb,
                    int Kdim, int conv, int domish)
{
    __shared__ __align__(16) bf16 la[2][192][64];   // 48 KiB
    __shared__ __align__(16) bf16 lb[2][256][64];   // 64 KiB  (112 total)
    const int tid = threadIdx.x;
    const int s0 = blockIdx.x * 256;
    const int o0 = blockIdx.y * 192;
    const int z  = blockIdx.z;
    out += (size_t)z * ozstr;
    Bm  += (size_t)z * bzstr;
    const int wv = tid >> 6, lane = tid & 63;
    const int wr = wv >> 2, wc = wv & 3;            // 2(M) x 4(N) waves
    const int l16 = lane & 15, q = lane >> 4;
    const int srow = lane >> 3;                     // staging row within 8-row strip
    const int schunk = (lane & 7) ^ srow;           // pre-swizzled source chunk
    const int nKt = Kdim >> 6;

    f32x4 acc[6][4];
    #pragma unroll
    for (int i = 0; i < 6; ++i)
        #pragma unroll
        for (int j = 0; j < 4; ++j)
            #pragma unroll
            for (int r = 0; r < 4; ++r) acc[i][j][r] = 0.f;

#define STAGE_A3(buf, kt) do {                                                \
    const bf16* gpA_ = Aw + (size_t)(o0 + wv * 8 + srow) * lda                \
                          + ((kt) << 6) + (schunk << 3);                      \
    __builtin_amdgcn_global_load_lds(GLB_PTR(gpA_),                           \
        LDS_PTR(&la[buf][wv * 8][0]), 16, 0, 0);                              \
    __builtin_amdgcn_global_load_lds(GLB_PTR(gpA_ + (size_t)64 * lda),        \
        LDS_PTR(&la[buf][64 + wv * 8][0]), 16, 0, 0);                         \
    __builtin_amdgcn_global_load_lds(GLB_PTR(gpA_ + (size_t)128 * lda),       \
        LDS_PTR(&la[buf][128 + wv * 8][0]), 16, 0, 0);                        \
} while (0)

#define STAGE_BL(buf, l, ro, bk) do {                                         \
    const bf16* gpB_ = Bm + (size_t)(s0 + (l) * 64 + wv * 8 + srow + (ro)) * ldb \
                          + (bk) + (schunk << 3);                             \
    __builtin_amdgcn_global_load_lds(GLB_PTR(gpB_),                           \
        LDS_PTR(&lb[buf][(l) * 64 + wv * 8][0]), 16, 0, 0);                   \
} while (0)

#define LDAF6(buf, kk) do {                                                   \
    _Pragma("unroll") for (int i2 = 0; i2 < 6; ++i2) {                        \
        int r_ = wr * 96 + i2 * 16 + l16;                                     \
        af[i2] = *(const bf16x8*)&la[buf][r_][(((kk) * 4 + q) ^ (r_ & 7)) << 3]; \
    }                                                                         \
} while (0)

#define LDBF4(buf, kk) do {                                                   \
    _Pragma("unroll") for (int j2 = 0; j2 < 4; ++j2) {                        \
        int r_ = wc * 64 + j2 * 16 + l16;                                     \
        bfr[j2] = *(const bf16x8*)&lb[buf][r_][(((kk) * 4 + q) ^ (r_ & 7)) << 3]; \
    }                                                                         \
} while (0)

#define MFMA24() do {                                                         \
    __builtin_amdgcn_s_setprio(1);                                            \
    _Pragma("unroll") for (int i2 = 0; i2 < 6; ++i2)                          \
    _Pragma("unroll") for (int j2 = 0; j2 < 4; ++j2)                          \
        acc[i2][j2] = __builtin_amdgcn_mfma_f32_16x16x32_bf16(                \
            af[i2], bfr[j2], acc[i2][j2], 0, 0, 0);                           \
    __builtin_amdgcn_s_setprio(0);                                            \
} while (0)

#define BARR()  __builtin_amdgcn_s_barrier()
#define WLGKM() asm volatile("s_waitcnt lgkmcnt(0)" ::: "memory")
#define WVM0()  asm volatile("s_waitcnt vmcnt(0)" ::: "memory")

    // prologue: stage tile 0 -> buf0 (7 loads), land, publish
    STAGE_A3(0, 0);
    STAGE_BL(0, 0, 0, 0); STAGE_BL(0, 1, 0, 0);
    STAGE_BL(0, 2, 0, 0); STAGE_BL(0, 3, 0, 0);
    WVM0();
    BARR();

    bf16x8 af[6], bfr[4];
    for (int t = 0; t < nKt; ++t) {
        const int c = t & 1, n = c ^ 1;
        const bool st = (t + 1) < nKt;
        int ro1 = 0, bk1 = (t + 1) << 6;
        if (conv) { ro1 = bk1 >> 9; bk1 &= 511; }
        // ---- phase 1 (kk=0): 10 reads; stage A(t+1)
        LDAF6(c, 0); LDBF4(c, 0);
        if (st) STAGE_A3(n, t + 1);
        BARR(); WLGKM();
        MFMA24();
        // ---- phase 2 (kk=1): 10 reads; stage B(t+1); publish tile t+1
        LDAF6(c, 1); LDBF4(c, 1);
        if (st) { STAGE_BL(n, 0, ro1, bk1); STAGE_BL(n, 1, ro1, bk1);
                  STAGE_BL(n, 2, ro1, bk1); STAGE_BL(n, 3, ro1, bk1); }
        BARR(); WLGKM();
        MFMA24();
        WVM0();
        BARR();
    }

    // C/D: col(lane&15)=s, row(q*4+reg)=o   [verified convention]
    #pragma unroll
    for (int i = 0; i < 6; ++i)
        #pragma unroll
        for (int j = 0; j < 4; ++j) {
            int sg = s0 + wc * 64 + j * 16 + l16;
            #pragma unroll
            for (int r = 0; r < 4; ++r) {
                int og = o0 + wr * 96 + i * 16 + q * 4 + r;
                float v = acc[i][j][r];
                if (domish) v = mishf(v);
                out[(size_t)og * S_ + sg] = v;
            }
        }
#undef STAGE_A3
#undef STAGE_BL
#undef LDAF6
#undef LDBF4
#undef MFMA24
#undef BARR
#undef WLGKM
#undef WVM0
}

// 128x128 GEMM (m97 structure) kept for the small w2 conv (M=256) + accumulate.
__global__ __launch_bounds__(256)
void gemm128_kernel(float* __restrict__ out, size_t ozstr,
                    const bf16* __restrict__ Aw, int lda,
                    const bf16* __restrict__ Bm, size_t bzstr, int ldb,
                    int Kdim, int conv, int addres)
{
    __shared__ __align__(16) bf16 la[128][64];
    __shared__ __align__(16) bf16 lb[128][64];
    const int tid = threadIdx.x;
    const int s0 = blockIdx.x * 128;
    const int o0 = blockIdx.y * 128;
    const int z  = blockIdx.z;
    out += (size_t)z * ozstr;
    Bm  += (size_t)z * bzstr;
    const int wv = tid >> 6, lane = tid & 63;
    const int wo = wv & 1, wsv = wv >> 1;
    const int l16 = lane & 15, q = lane >> 4;
    const int lrow = lane >> 3, lslot = lane & 7;

    f32x4 acc[4][4];
    #pragma unroll
    for (int i = 0; i < 4; ++i)
        #pragma unroll
        for (int j = 0; j < 4; ++j)
            #pragma unroll
            for (int r = 0; r < 4; ++r) acc[i][j][r] = 0.f;

    for (int k0 = 0; k0 < Kdim; k0 += 64) {
        int roff = 0, bk = k0;
        if (conv) { roff = k0 >> 9; bk = k0 & 511; }
        __syncthreads();
        #pragma unroll
        for (int t = 0; t < 4; ++t) {
            int rbase = wv * 32 + t * 8;
            int row = rbase + lrow;
            int chunk = lslot ^ (row & 7);
            __builtin_amdgcn_global_load_lds(
                GLB_PTR(Aw + (size_t)(o0 + row) * lda + k0 + chunk * 8),
                LDS_PTR(&la[rbase][0]), 16, 0, 0);
        }
        #pragma unroll
        for (int t = 0; t < 4; ++t) {
            int rbase = wv * 32 + t * 8;
            int row = rbase + lrow;
            int chunk = lslot ^ (row & 7);
            __builtin_amdgcn_global_load_lds(
                GLB_PTR(Bm + (size_t)(s0 + row + roff) * ldb + bk + chunk * 8),
                LDS_PTR(&lb[rbase][0]), 16, 0, 0);
        }
        __syncthreads();
        #pragma unroll
        for (int kk = 0; kk < 2; ++kk) {
            bf16x8 af[4], bfr[4];
            #pragma unroll
            for (int i = 0; i < 4; ++i) {
                int r = wo * 64 + i * 16 + l16;
                int c = kk * 4 + q;
                af[i] = *(const bf16x8*)&la[r][(c ^ (r & 7)) * 8];
            }
            #pragma unroll
            for (int j = 0; j < 4; ++j) {
                int r = wsv * 64 + j * 16 + l16;
                int c = kk * 4 + q;
                bfr[j] = *(const bf16x8*)&lb[r][(c ^ (r & 7)) * 8];
            }
            #pragma unroll
            for (int i = 0; i < 4; ++i)
                #pragma unroll
                for (int j = 0; j < 4; ++j)
                    acc[i][j] = __builtin_amdgcn_mfma_f32_16x16x32_bf16(
                        af[i], bfr[j], acc[i][j], 0, 0, 0);
        }
    }
    #pragma unroll
    for (int i = 0; i < 4; ++i)
        #pragma unroll
        for (int j = 0; j < 4; ++j) {
            int sg = s0 + wsv * 64 + j * 16 + l16;
            #pragma unroll
            for (int r = 0; r < 4; ++r) {
                int og = o0 + wo * 64 + i * 16 + q * 4 + r;
                float v = acc[i][j][r];
                if (addres) v += out[(size_t)og * S_ + sg];
                out[(size_t)og * S_ + sg] = v;
            }
        }
}

__global__ __launch_bounds__(256)
void final_kernel(void* __restrict__ out, const float* __restrict__ x0,
                  const float* __restrict__ x1, const void* __restrict__ ow,
                  const void* __restrict__ ob, const int* __restrict__ flag)
{
    __shared__ float wl[16][68];
    __shared__ float xl[16][68];
    const int isbf = flag[0];
    const int tid = threadIdx.x;
    const int tx = tid & 15, ty = tid >> 4;
    const int s0 = blockIdx.x * 64;
    const int o0 = blockIdx.y * 64;
    const int b  = blockIdx.z;
    float acc[4][4] = {};
    for (int c0 = 0; c0 < 2 * F_; c0 += 16) {
        if (isbf) {
            #pragma unroll
            for (int e = tid; e < 1024; e += 256) {
                int k = e & 15, o = e >> 4;
                wl[k][o] = __bfloat162float(((const bf16*)ow)[(size_t)(o0 + o) * (2 * F_) + (c0 + k)]);
            }
        } else {
            #pragma unroll
            for (int e = tid; e < 1024; e += 256) {
                int k = e & 15, o = e >> 4;
                wl[k][o] = ((const float*)ow)[(size_t)(o0 + o) * (2 * F_) + (c0 + k)];
            }
        }
        {
            int r = tid >> 4;
            int qq = (tid & 15) * 4;
            int cr = c0 + r;
            const float* src = (cr < F_) ? (x0 + ((size_t)b * F_ + cr) * S_)
                                         : (x1 + ((size_t)b * F_ + (cr - F_)) * S_);
            *(float4*)&xl[r][qq] = *(const float4*)(src + s0 + qq);
        }
        __syncthreads();
        #pragma unroll
        for (int k = 0; k < 16; ++k) {
            float4 av = *(const float4*)&wl[k][ty * 4];
            float4 bv = *(const float4*)&xl[k][tx * 4];
            #pragma unroll
            for (int i = 0; i < 4; ++i)
                #pragma unroll
                for (int j = 0; j < 4; ++j)
                    acc[i][j] += (&av.x)[i] * (&bv.x)[j];
        }
        __syncthreads();
    }
    #pragma unroll
    for (int i = 0; i < 4; ++i) {
        int o = o0 + ty * 4 + i;
        float bias = loadw(ob, o, isbf);
        size_t outoff = ((size_t)b * V_ + o) * S_ + s0 + tx * 4;
        if (isbf) {
            bf16* po = (bf16*)out + outoff;
            #pragma unroll
            for (int j = 0; j < 4; ++j)
                po[j] = __float2bfloat16(acc[i][j] + bias);
        } else {
            float* po = (float*)out + outoff;
            *(float4*)po = make_float4(acc[i][0] + bias, acc[i][1] + bias,
                                       acc[i][2] + bias, acc[i][3] + bias);
        }
    }
}

extern "C" void kernel_launch(void* const* d_in, const int* in_sizes, int n_in,
                              void* d_out, int out_size, void* d_ws, size_t ws_size,
                              hipStream_t stream)
{
    const int*  inp  = (const int*)d_in[0];
    const void* emb  = d_in[1];
    const void* w0   = d_in[2];
    const void* w1   = d_in[3];
    const void* w2   = d_in[4];
    const void* outw = d_in[5];
    const void* outb = d_in[6];

    const size_t NX = (size_t)B_ * F_ * S_;
    const size_t NT = (size_t)I3_ * S_;
    const size_t NV = (size_t)I_ * S_;
    const size_t VSTR = (size_t)VR_ * I_;     // vbt z-stride (elements)

    // P = batch slices processed per dispatch; pick largest fitting ws_size.
    auto need = [&](int p) -> size_t {
        return 256 + 8 * NX + (size_t)4 * p * NT + (size_t)2 * p * NV
             + 2 * ((size_t)I3_ * KE_ + (size_t)p * VSTR + (size_t)p * S_ * F_
                    + (size_t)I3_ * F_ + (size_t)F_ * I_);
    };
    int P = 2;
    if (ws_size >= need(8)) P = 8;
    else if (ws_size >= need(4)) P = 4;

    int*   flag = (int*)d_ws;
    float* A  = (float*)d_ws + 64;
    float* Bb = A + NX;
    float* T  = Bb + NX;                       // P slices, fp32 (pre-mished)
    bf16*  Vv = (bf16*)(T + (size_t)P * NT);   // P slices, bf16
    bf16*  wexp = Vv + (size_t)P * NV;
    bf16*  vbt  = wexp + (size_t)I3_ * KE_;    // P slices, 6-row zero pad each
    bf16*  xbt  = vbt + (size_t)P * VSTR;      // P slices
    bf16*  wb0  = xbt + (size_t)P * S_ * F_;
    bf16*  wb2  = wb0 + (size_t)I3_ * F_;

    detect_kernel<<<1, 256, 0, stream>>>(flag, (const unsigned short*)emb);
    embed_kernel<<<dim3((unsigned)(NX / 256)), 256, 0, stream>>>(A, Bb, inp, emb, flag);
    zeropad_kernel<<<dim3((P * 6 * I_ + 255) / 256), 256, 0, stream>>>(vbt, P);

    int swap = 0;
    for (int d = 0; d < D_; ++d) {
        wexp_kernel<<<dim3(I3_ * I_ / 256), 256, 0, stream>>>(
            wexp, w1, (size_t)d * I3_ * I_ * K_, flag);
        cvt_kernel<<<dim3(I3_ * F_ / 256), 256, 0, stream>>>(
            wb0, w0, (size_t)d * I3_ * F_, I3_ * F_, flag);
        cvt_kernel<<<dim3(F_ * I_ / 256), 256, 0, stream>>>(
            wb2, w2, (size_t)d * F_ * I_, F_ * I_, flag);
        for (int bp = 0; bp < B_ / P; ++bp) {
            float* x0 = (swap ? Bb : A) + (size_t)(P * bp) * F_ * S_;
            float* x1 = (swap ? A : Bb) + (size_t)(P * bp) * F_ * S_;
            // xbt[z] = x1(b)^T bf16
            trans_kernel<<<dim3(S_ / 64, F_ / 64, P), 256, 0, stream>>>(
                xbt, (size_t)S_ * F_, x1, (size_t)F_ * S_, F_);
            // T[z] = mish(wb0 @ xbt[z])   (192x256-tile, grid 16*8*P = 512)
            gemm192_kernel<<<dim3(S_ / 256, I3_ / 192, P), 512, 0, stream>>>(
                T, NT, wb0, F_, xbt, (size_t)S_ * F_, F_, F_, 0, 1);
            scan_kernel<<<dim3(I_, P), 256, 0, stream>>>(Vv, T);
            // vbt[z] rows 6.. = Vv[z]^T (pad rows 0..5 stay zero)
            transb_kernel<<<dim3(S_ / 64, I_ / 64, P), 256, 0, stream>>>(
                vbt + 6 * I_, VSTR, Vv, NV, I_);
            // T[z] = mish(causal conv as flattened-K GEMM)
            gemm192_kernel<<<dim3(S_ / 256, I3_ / 192, P), 512, 0, stream>>>(
                T, NT, wexp, KE_, vbt, VSTR, I_, KE_, 1, 1);
            scan_kernel<<<dim3(I_, P), 256, 0, stream>>>(Vv, T);
            transb_kernel<<<dim3(S_ / 64, I_ / 64, P), 256, 0, stream>>>(
                vbt + 6 * I_, VSTR, Vv, NV, I_);
            // x0(b) += wb2 @ v[z]   (small M=256: keep 128-tile kernel, grid 256)
            gemm128_kernel<<<dim3(S_ / 128, F_ / 128, P), 256, 0, stream>>>(
                x0, (size_t)F_ * S_, wb2, I_, vbt + 6 * I_, VSTR, I_, I_, 0, 1);
        }
        swap ^= 1;
    }
    final_kernel<<<dim3(S_ / 64, V_ / 64, B_), 256, 0, stream>>>(d_out, A, Bb, outw, outb, flag);
    (void)in_sizes; (void)n_in; (void)out_size;
}

// Round 8
// 2648.505 us; speedup vs baseline: 1.0970x; 1.0006x over previous
//
#include <hip/hip_runtime.h>
#include <hip/hip_bf16.h>

#define B_ 8
#define S_ 4096
#define F_ 256
#define I_ 512
#define D_ 4
#define K_ 7
#define V_ 256
#define I3_ 1536
#define KE_ 3584           // 7*512 flattened causal-conv K
#define VR_ (S_ + 8)       // vbt rows: 6 zero-pad + 4096 + 2 slack

using bf16 = __hip_bfloat16;
typedef __bf16 bf16x8 __attribute__((ext_vector_type(8)));
typedef float  f32x4  __attribute__((ext_vector_type(4)));

#define LDS_PTR(p) ((__attribute__((address_space(3))) void*)(p))
#define GLB_PTR(p) ((const __attribute__((address_space(1))) void*)(p))

#define BARR_()  __builtin_amdgcn_s_barrier()
#define WLGKM_() asm volatile("s_waitcnt lgkmcnt(0)" ::: "memory")
#define WVM0_()  asm volatile("s_waitcnt vmcnt(0)" ::: "memory")

// mish(x) = x*tanh(softplus(x)) = x*(u^2+2u)/(u^2+2u+2), u=e^x (exact closed form).
__device__ __forceinline__ float mishf(float x) {
    float u = expf(fminf(x, 30.0f));
    float t = u * (u + 2.0f);
    return x * (t / (t + 2.0f));
}

__device__ __forceinline__ float loadw(const void* p, size_t i, int isbf) {
    return isbf ? __bfloat162float(((const bf16*)p)[i]) : ((const float*)p)[i];
}

__device__ __forceinline__ __bf16 tobf(float x) {
    bf16 h = __float2bfloat16(x);
    return *(__bf16*)&h;
}

// bf16 buffers of small weights never show bf16-exponent>=132 (|x|>=32);
// fp32 buffers read as uint16 do (random mantissa bits in low halves).
__global__ __launch_bounds__(256)
void detect_kernel(int* __restrict__ flag, const unsigned short* __restrict__ p)
{
    __shared__ int sh[256];
    int cnt = 0;
    for (int j = threadIdx.x; j < 16384; j += 256) {
        unsigned int e = (p[j] >> 7) & 0xffu;
        if (e >= 132u) cnt++;
    }
    sh[threadIdx.x] = cnt;
    __syncthreads();
    for (int s = 128; s > 0; s >>= 1) {
        if ((int)threadIdx.x < s) sh[threadIdx.x] += sh[threadIdx.x + s];
        __syncthreads();
    }
    if (threadIdx.x == 0) flag[0] = (sh[0] == 0) ? 1 : 0;   // 1 => bf16 inputs
}

__global__ __launch_bounds__(256)
void embed_kernel(float* __restrict__ x0, float* __restrict__ x1,
                  const int* __restrict__ inp, const void* __restrict__ emb,
                  const int* __restrict__ flag)
{
    const int isbf = flag[0];
    size_t idx = (size_t)blockIdx.x * 256 + threadIdx.x;   // over B*F*S
    int s = (int)(idx % S_);
    int f = (int)((idx / S_) % F_);
    int b = (int)(idx / ((size_t)S_ * F_));
    int tok = inp[b * S_ + s];
    x0[idx] = loadw(emb, (size_t)tok * (2 * F_) + f, isbf);
    x1[idx] = loadw(emb, (size_t)tok * (2 * F_) + F_ + f, isbf);
}

// zero the 6 pad rows of all P vbt slices (re-poisoned every call)
__global__ __launch_bounds__(256)
void zeropad_kernel(bf16* __restrict__ vbt, int nslice)
{
    int i = blockIdx.x * 256 + threadIdx.x;
    if (i < nslice * 6 * I_) {
        int z = i / (6 * I_), off = i % (6 * I_);
        vbt[(size_t)z * VR_ * I_ + off] = __float2bfloat16(0.0f);
    }
}

// merged per-depth weight prep (one dispatch instead of three):
//   job 0: wexp [o][k*512+c] <- w1 [o][c][k]   (I3*I indices)
//   job 1: wb0[i] <- (bf16)w0[o0w + i]         (I3*F indices)
//   job 2: wb2[i] <- (bf16)w2[o2w + i]         (F*I indices)
__global__ __launch_bounds__(256)
void wprep_kernel(bf16* __restrict__ wexp, bf16* __restrict__ wb0,
                  bf16* __restrict__ wb2, const void* __restrict__ w1,
                  const void* __restrict__ w0, const void* __restrict__ w2,
                  size_t o1w, size_t o0w, size_t o2w, const int* __restrict__ flag)
{
    const int isbf = flag[0];
    int idx = blockIdx.x * 256 + threadIdx.x;
    if (idx < I3_ * I_) {
        int c = idx & 511, o = idx >> 9;
        const size_t base = o1w + ((size_t)o * 512 + c) * 7;
        float vals[7];
        #pragma unroll
        for (int k = 0; k < 7; ++k) vals[k] = loadw(w1, base + k, isbf);
        #pragma unroll
        for (int k = 0; k < 7; ++k)
            wexp[(size_t)o * KE_ + (k << 9) + c] = __float2bfloat16(vals[k]);
    } else if (idx < I3_ * I_ + I3_ * F_) {
        int i = idx - I3_ * I_;
        wb0[i] = __float2bfloat16(loadw(w0, o0w + i, isbf));
    } else if (idx < I3_ * I_ + I3_ * F_ + F_ * I_) {
        int i = idx - I3_ * I_ - I3_ * F_;
        wb2[i] = __float2bfloat16(loadw(w2, o2w + i, isbf));
    }
}

// Inputs t are PRE-MISHED by the gemm epilogue.
// v[i,s] = cumsum_s(t[i,s])/(s+1) * t[I+i,s] + t[2I+i,s]; bf16 output.
// grid (I_, P): blockIdx.y = z scratch slice
__global__ __launch_bounds__(256)
void scan_kernel(bf16* __restrict__ vout, const float* __restrict__ t)
{
    const int z = blockIdx.y;
    const int i = blockIdx.x;
    t    += (size_t)z * I3_ * S_;
    vout += (size_t)z * I_ * S_;
    const float* dp  = t + (size_t)i * S_;
    const float* scp = dp + (size_t)I_ * S_;
    const float* shp = dp + (size_t)(2 * I_) * S_;
    bf16* op = vout + (size_t)i * S_;
    const int tid = threadIdx.x;
    const int base = tid * 16;

    float md[16];
    float lsum = 0.f;
    #pragma unroll
    for (int q = 0; q < 4; ++q) {
        float4 dv = *(const float4*)(dp + base + q * 4);
        #pragma unroll
        for (int j = 0; j < 4; ++j) {
            float m = (&dv.x)[j];
            md[q * 4 + j] = m;
            lsum += m;
        }
    }
    float ssum = lsum;
    #pragma unroll
    for (int off = 1; off < 64; off <<= 1) {
        float nv = __shfl_up(ssum, off, 64);
        if ((tid & 63) >= off) ssum += nv;
    }
    __shared__ float wtot[4];
    const int wid = tid >> 6, lane = tid & 63;
    if (lane == 63) wtot[wid] = ssum;
    __syncthreads();
    float excl = ssum - lsum;
    #pragma unroll
    for (int wq = 0; wq < 3; ++wq)
        if (wq < wid) excl += wtot[wq];

    float run = excl;
    bf16x8 o0v, o1v;
    #pragma unroll
    for (int q = 0; q < 4; ++q) {
        float4 scv = *(const float4*)(scp + base + q * 4);
        float4 shv = *(const float4*)(shp + base + q * 4);
        #pragma unroll
        for (int j = 0; j < 4; ++j) {
            run += md[q * 4 + j];
            float sdiv = (float)(base + q * 4 + j + 1);
            float ov = run / sdiv * (&scv.x)[j] + (&shv.x)[j];
            if (q < 2) o0v[q * 4 + j] = tobf(ov);
            else       o1v[(q - 2) * 4 + j] = tobf(ov);
        }
    }
    *(bf16x8*)(void*)(op + base) = o0v;
    *(bf16x8*)(void*)(op + base + 8) = o1v;
}

// src fp32 [C][S_] (+z*szstr) -> dst bf16 [S_][C] (+z*dzstr); 64x64 LDS tile
__global__ __launch_bounds__(256)
void trans_kernel(bf16* __restrict__ dst, size_t dzstr,
                  const float* __restrict__ src, size_t szstr, int C)
{
    __shared__ __align__(16) bf16 lt[64][72];
    const int z = blockIdx.z;
    dst += (size_t)z * dzstr;
    src += (size_t)z * szstr;
    const int tid = threadIdx.x;
    const int s0 = blockIdx.x * 64;
    const int c0 = blockIdx.y * 64;
    #pragma unroll
    for (int p = 0; p < 4; ++p) {
        int c = p * 16 + (tid >> 4);
        int sc = (tid & 15) * 4;
        float4 f = *(const float4*)(src + (size_t)(c0 + c) * S_ + s0 + sc);
        #pragma unroll
        for (int j = 0; j < 4; ++j)
            lt[sc + j][c] = __float2bfloat16((&f.x)[j]);
    }
    __syncthreads();
    #pragma unroll
    for (int p = 0; p < 2; ++p) {
        int ch = p * 256 + tid;
        int r = ch >> 3, g = ch & 7;
        *(bf16x8*)(dst + (size_t)(s0 + r) * C + c0 + g * 8) =
            *(const bf16x8*)&lt[r][g * 8];
    }
}

// src bf16 [C][S_] (+z*szstr) -> dst bf16 [S_][C] (+z*dzstr); 64x64 LDS tile
__global__ __launch_bounds__(256)
void transb_kernel(bf16* __restrict__ dst, size_t dzstr,
                   const bf16* __restrict__ src, size_t szstr, int C)
{
    __shared__ __align__(16) bf16 lt[64][72];
    const int z = blockIdx.z;
    dst += (size_t)z * dzstr;
    src += (size_t)z * szstr;
    const int tid = threadIdx.x;
    const int s0 = blockIdx.x * 64;
    const int c0 = blockIdx.y * 64;
    #pragma unroll
    for (int p = 0; p < 2; ++p) {
        int c = p * 32 + (tid >> 3);
        int sc = (tid & 7) * 8;
        bf16x8 v = *(const bf16x8*)(src + (size_t)(c0 + c) * S_ + s0 + sc);
        #pragma unroll
        for (int j = 0; j < 8; ++j)
            *(__bf16*)&lt[sc + j][c] = v[j];
    }
    __syncthreads();
    #pragma unroll
    for (int p = 0; p < 2; ++p) {
        int ch = p * 256 + tid;
        int r = ch >> 3, g = ch & 7;
        *(bf16x8*)(dst + (size_t)(s0 + r) * C + c0 + g * 8) =
            *(const bf16x8*)&lt[r][g * 8];
    }
}

// ---------------------------------------------------------------------------
// 192(o) x 256(s) tile GEMM, double-buffered LDS (112 KiB), TWO phases and
// TWO barriers per K-tile (was 3: ph2's pre-MFMA barrier doubles as the
// tile-publish barrier, with the per-wave vmcnt(0) hoisted before it).
// Grid = 16 x 8 x P = 512 (P=4): exact 2 rounds over 256 CUs.
// 8 waves (2M x 4N); per-wave 96o x 64s; acc[6][4].
// Tile t (buf c=t&1):
//   ph1: {10 ds_read (kk0) || ALL 7 stages for t+1 -> buf n} BARR lgkm MFMA24
//   ph2: {10 ds_read (kk1)} WVM0 BARR lgkm MFMA24
// RAW: WVM0 is per-wave exact (only its own 7 stages are in vmcnt), with
//      ph1's MFMA24 (~470cyc) + read-issue as latency cover; the ph2 BARR
//      then publishes tile t+1 before any wave's tile-t+1 reads (program
//      order: next ph1 reads come after this barrier).
// WAR: buf n's last reads are t-1 ph2's kk1 reads, drained by each wave's
//      own lgkm right after the t-1 ph2 barrier; any wave's restage issue is
//      >= one full MFMA24 after that same barrier -> no overlap.
// Pacing barriers before each MFMA kept (R4/m196: removing them -> 29%).
// domish: fused mish on the fp32 result (feeds scan_kernel).
// ---------------------------------------------------------------------------
__global__ __launch_bounds__(512, 1)
void gemm192_kernel(float* __restrict__ out, size_t ozstr,
                    const bf16* __restrict__ Aw, int lda,
                    const bf16* __restrict__ Bm, size_t bzstr, int ldb,
                    int Kdim, int conv, int domish)
{
    __shared__ __align__(16) bf16 la[2][192][64];   // 48 KiB
    __shared__ __align__(16) bf16 lb[2][256][64];   // 64 KiB  (112 total)
    const int tid = threadIdx.x;
    const int s0 = blockIdx.x * 256;
    const int o0 = blockIdx.y * 192;
    const int z  = blockIdx.z;
    out += (size_t)z * ozstr;
    Bm  += (size_t)z * bzstr;
    const int wv = tid >> 6, lane = tid & 63;
    const int wr = wv >> 2, wc = wv & 3;            // 2(M) x 4(N) waves
    const int l16 = lane & 15, q = lane >> 4;
    const int srow = lane >> 3;                     // staging row within 8-row strip
    const int schunk = (lane & 7) ^ srow;           // pre-swizzled source chunk
    const int nKt = Kdim >> 6;

    f32x4 acc[6][4];
    #pragma unroll
    for (int i = 0; i < 6; ++i)
        #pragma unroll
        for (int j = 0; j < 4; ++j)
            #pragma unroll
            for (int r = 0; r < 4; ++r) acc[i][j][r] = 0.f;

#define STAGE_A3(buf, kt) do {                                                \
    const bf16* gpA_ = Aw + (size_t)(o0 + wv * 8 + srow) * lda                \
                          + ((kt) << 6) + (schunk << 3);                      \
    __builtin_amdgcn_global_load_lds(GLB_PTR(gpA_),                           \
        LDS_PTR(&la[buf][wv * 8][0]), 16, 0, 0);                              \
    __builtin_amdgcn_global_load_lds(GLB_PTR(gpA_ + (size_t)64 * lda),        \
        LDS_PTR(&la[buf][64 + wv * 8][0]), 16, 0, 0);                         \
    __builtin_amdgcn_global_load_lds(GLB_PTR(gpA_ + (size_t)128 * lda),       \
        LDS_PTR(&la[buf][128 + wv * 8][0]), 16, 0, 0);                        \
} while (0)

#define STAGE_BL(buf, l, ro, bk) do {                                         \
    const bf16* gpB_ = Bm + (size_t)(s0 + (l) * 64 + wv * 8 + srow + (ro)) * ldb \
                          + (bk) + (schunk << 3);                             \
    __builtin_amdgcn_global_load_lds(GLB_PTR(gpB_),                           \
        LDS_PTR(&lb[buf][(l) * 64 + wv * 8][0]), 16, 0, 0);                   \
} while (0)

#define LDAF6(buf, kk) do {                                                   \
    _Pragma("unroll") for (int i2 = 0; i2 < 6; ++i2) {                        \
        int r_ = wr * 96 + i2 * 16 + l16;                                     \
        af[i2] = *(const bf16x8*)&la[buf][r_][(((kk) * 4 + q) ^ (r_ & 7)) << 3]; \
    }                                                                         \
} while (0)

#define LDBF4(buf, kk) do {                                                   \
    _Pragma("unroll") for (int j2 = 0; j2 < 4; ++j2) {                        \
        int r_ = wc * 64 + j2 * 16 + l16;                                     \
        bfr[j2] = *(const bf16x8*)&lb[buf][r_][(((kk) * 4 + q) ^ (r_ & 7)) << 3]; \
    }                                                                         \
} while (0)

#define MFMA24() do {                                                         \
    __builtin_amdgcn_s_setprio(1);                                            \
    _Pragma("unroll") for (int i2 = 0; i2 < 6; ++i2)                          \
    _Pragma("unroll") for (int j2 = 0; j2 < 4; ++j2)                          \
        acc[i2][j2] = __builtin_amdgcn_mfma_f32_16x16x32_bf16(                \
            af[i2], bfr[j2], acc[i2][j2], 0, 0, 0);                           \
    __builtin_amdgcn_s_setprio(0);                                            \
} while (0)

    // prologue: stage tile 0 -> buf0 (7 loads), land, publish
    STAGE_A3(0, 0);
    STAGE_BL(0, 0, 0, 0); STAGE_BL(0, 1, 0, 0);
    STAGE_BL(0, 2, 0, 0); STAGE_BL(0, 3, 0, 0);
    WVM0_();
    BARR_();

    bf16x8 af[6], bfr[4];
    for (int t = 0; t < nKt; ++t) {
        const int c = t & 1, n = c ^ 1;
        const bool st = (t + 1) < nKt;
        int ro1 = 0, bk1 = (t + 1) << 6;
        if (conv) { ro1 = bk1 >> 9; bk1 &= 511; }
        // ---- phase 1 (kk=0): 10 reads; ALL stages for tile t+1
        LDAF6(c, 0); LDBF4(c, 0);
        if (st) {
            STAGE_A3(n, t + 1);
            STAGE_BL(n, 0, ro1, bk1); STAGE_BL(n, 1, ro1, bk1);
            STAGE_BL(n, 2, ro1, bk1); STAGE_BL(n, 3, ro1, bk1);
        }
        BARR_(); WLGKM_();
        MFMA24();
        // ---- phase 2 (kk=1): 10 reads; per-wave stage drain; publish+pace
        LDAF6(c, 1); LDBF4(c, 1);
        if (st) WVM0_();
        BARR_(); WLGKM_();
        MFMA24();
    }

    // C/D: col(lane&15)=s, row(q*4+reg)=o   [verified convention]
    #pragma unroll
    for (int i = 0; i < 6; ++i)
        #pragma unroll
        for (int j = 0; j < 4; ++j) {
            int sg = s0 + wc * 64 + j * 16 + l16;
            #pragma unroll
            for (int r = 0; r < 4; ++r) {
                int og = o0 + wr * 96 + i * 16 + q * 4 + r;
                float v = acc[i][j][r];
                if (domish) v = mishf(v);
                out[(size_t)og * S_ + sg] = v;
            }
        }
#undef STAGE_A3
#undef STAGE_BL
#undef LDAF6
#undef LDBF4
#undef MFMA24
}

// 128x128 GEMM for the small w2 conv (M=256) + accumulate.
// Upgraded to the same double-buffered 2-barrier schedule as gemm192.
// Grid = 32 x 2 x P = 256 (P=4): exact 1 round. 4 waves; per-wave 64x64.
__global__ __launch_bounds__(256)
void gemm128_kernel(float* __restrict__ out, size_t ozstr,
                    const bf16* __restrict__ Aw, int lda,
                    const bf16* __restrict__ Bm, size_t bzstr, int ldb,
                    int Kdim, int conv, int addres)
{
    __shared__ __align__(16) bf16 la[2][128][64];   // 32 KiB
    __shared__ __align__(16) bf16 lb[2][128][64];   // 32 KiB (64 total)
    const int tid = threadIdx.x;
    const int s0 = blockIdx.x * 128;
    const int o0 = blockIdx.y * 128;
    const int z  = blockIdx.z;
    out += (size_t)z * ozstr;
    Bm  += (size_t)z * bzstr;
    const int wv = tid >> 6, lane = tid & 63;
    const int wo = wv & 1, wsv = wv >> 1;
    const int l16 = lane & 15, q = lane >> 4;
    const int lrow = lane >> 3, lslot = lane & 7;
    const int nKt = Kdim >> 6;

    f32x4 acc[4][4];
    #pragma unroll
    for (int i = 0; i < 4; ++i)
        #pragma unroll
        for (int j = 0; j < 4; ++j)
            #pragma unroll
            for (int r = 0; r < 4; ++r) acc[i][j][r] = 0.f;

#define G128_STAGE(buf, kt) do {                                              \
    int k0_ = (kt) << 6; int roff_ = 0, bk_ = k0_;                            \
    if (conv) { roff_ = k0_ >> 9; bk_ = k0_ & 511; }                          \
    _Pragma("unroll") for (int t_ = 0; t_ < 4; ++t_) {                        \
        int rbase = wv * 32 + t_ * 8;                                         \
        int row = rbase + lrow;                                               \
        int chunk = lslot ^ (row & 7);                                        \
        __builtin_amdgcn_global_load_lds(                                     \
            GLB_PTR(Aw + (size_t)(o0 + row) * lda + k0_ + chunk * 8),         \
            LDS_PTR(&la[buf][rbase][0]), 16, 0, 0);                           \
        __builtin_amdgcn_global_load_lds(                                     \
            GLB_PTR(Bm + (size_t)(s0 + row + roff_) * ldb + bk_ + chunk * 8), \
            LDS_PTR(&lb[buf][rbase][0]), 16, 0, 0);                           \
    }                                                                         \
} while (0)

#define G128_RD(buf, kk) do {                                                 \
    _Pragma("unroll") for (int i = 0; i < 4; ++i) {                           \
        int r = wo * 64 + i * 16 + l16;                                       \
        af[i] = *(const bf16x8*)&la[buf][r][(((kk) * 4 + q) ^ (r & 7)) * 8];  \
    }                                                                         \
    _Pragma("unroll") for (int j = 0; j < 4; ++j) {                           \
        int r = wsv * 64 + j * 16 + l16;                                      \
        bfr[j] = *(const bf16x8*)&lb[buf][r][(((kk) * 4 + q) ^ (r & 7)) * 8]; \
    }                                                                         \
} while (0)

#define G128_MFMA16() do {                                                    \
    __builtin_amdgcn_s_setprio(1);                                            \
    _Pragma("unroll") for (int i = 0; i < 4; ++i)                             \
    _Pragma("unroll") for (int j = 0; j < 4; ++j)                             \
        acc[i][j] = __builtin_amdgcn_mfma_f32_16x16x32_bf16(                  \
            af[i], bfr[j], acc[i][j], 0, 0, 0);                               \
    __builtin_amdgcn_s_setprio(0);                                            \
} while (0)

    G128_STAGE(0, 0);
    WVM0_();
    BARR_();

    bf16x8 af[4], bfr[4];
    for (int t = 0; t < nKt; ++t) {
        const int c = t & 1, n = c ^ 1;
        const bool st = (t + 1) < nKt;
        // ph1: reads kk0 + all 8 stages for t+1
        G128_RD(c, 0);
        if (st) G128_STAGE(n, t + 1);
        BARR_(); WLGKM_();
        G128_MFMA16();
        // ph2: reads kk1; per-wave drain; publish+pace barrier
        G128_RD(c, 1);
        if (st) WVM0_();
        BARR_(); WLGKM_();
        G128_MFMA16();
    }

    #pragma unroll
    for (int i = 0; i < 4; ++i)
        #pragma unroll
        for (int j = 0; j < 4; ++j) {
            int sg = s0 + wsv * 64 + j * 16 + l16;
            #pragma unroll
            for (int r = 0; r < 4; ++r) {
                int og = o0 + wo * 64 + i * 16 + q * 4 + r;
                float v = acc[i][j][r];
                if (addres) v += out[(size_t)og * S_ + sg];
                out[(size_t)og * S_ + sg] = v;
            }
        }
#undef G128_STAGE
#undef G128_RD
#undef G128_MFMA16
}

__global__ __launch_bounds__(256)
void final_kernel(void* __restrict__ out, const float* __restrict__ x0,
                  const float* __restrict__ x1, const void* __restrict__ ow,
                  const void* __restrict__ ob, const int* __restrict__ flag)
{
    __shared__ float wl[16][68];
    __shared__ float xl[16][68];
    const int isbf = flag[0];
    const int tid = threadIdx.x;
    const int tx = tid & 15, ty = tid >> 4;
    const int s0 = blockIdx.x * 64;
    const int o0 = blockIdx.y * 64;
    const int b  = blockIdx.z;
    float acc[4][4] = {};
    for (int c0 = 0; c0 < 2 * F_; c0 += 16) {
        if (isbf) {
            #pragma unroll
            for (int e = tid; e < 1024; e += 256) {
                int k = e & 15, o = e >> 4;
                wl[k][o] = __bfloat162float(((const bf16*)ow)[(size_t)(o0 + o) * (2 * F_) + (c0 + k)]);
            }
        } else {
            #pragma unroll
            for (int e = tid; e < 1024; e += 256) {
                int k = e & 15, o = e >> 4;
                wl[k][o] = ((const float*)ow)[(size_t)(o0 + o) * (2 * F_) + (c0 + k)];
            }
        }
        {
            int r = tid >> 4;
            int qq = (tid & 15) * 4;
            int cr = c0 + r;
            const float* src = (cr < F_) ? (x0 + ((size_t)b * F_ + cr) * S_)
                                         : (x1 + ((size_t)b * F_ + (cr - F_)) * S_);
            *(float4*)&xl[r][qq] = *(const float4*)(src + s0 + qq);
        }
        __syncthreads();
        #pragma unroll
        for (int k = 0; k < 16; ++k) {
            float4 av = *(const float4*)&wl[k][ty * 4];
            float4 bv = *(const float4*)&xl[k][tx * 4];
            #pragma unroll
            for (int i = 0; i < 4; ++i)
                #pragma unroll
                for (int j = 0; j < 4; ++j)
                    acc[i][j] += (&av.x)[i] * (&bv.x)[j];
        }
        __syncthreads();
    }
    #pragma unroll
    for (int i = 0; i < 4; ++i) {
        int o = o0 + ty * 4 + i;
        float bias = loadw(ob, o, isbf);
        size_t outoff = ((size_t)b * V_ + o) * S_ + s0 + tx * 4;
        if (isbf) {
            bf16* po = (bf16*)out + outoff;
            #pragma unroll
            for (int j = 0; j < 4; ++j)
                po[j] = __float2bfloat16(acc[i][j] + bias);
        } else {
            float* po = (float*)out + outoff;
            *(float4*)po = make_float4(acc[i][0] + bias, acc[i][1] + bias,
                                       acc[i][2] + bias, acc[i][3] + bias);
        }
    }
}

extern "C" void kernel_launch(void* const* d_in, const int* in_sizes, int n_in,
                              void* d_out, int out_size, void* d_ws, size_t ws_size,
                              hipStream_t stream)
{
    const int*  inp  = (const int*)d_in[0];
    const void* emb  = d_in[1];
    const void* w0   = d_in[2];
    const void* w1   = d_in[3];
    const void* w2   = d_in[4];
    const void* outw = d_in[5];
    const void* outb = d_in[6];

    const size_t NX = (size_t)B_ * F_ * S_;
    const size_t NT = (size_t)I3_ * S_;
    const size_t NV = (size_t)I_ * S_;
    const size_t VSTR = (size_t)VR_ * I_;     // vbt z-stride (elements)

    // P = batch slices processed per dispatch; pick largest fitting ws_size.
    auto need = [&](int p) -> size_t {
        return 256 + 8 * NX + (size_t)4 * p * NT + (size_t)2 * p * NV
             + 2 * ((size_t)I3_ * KE_ + (size_t)p * VSTR + (size_t)p * S_ * F_
                    + (size_t)I3_ * F_ + (size_t)F_ * I_);
    };
    int P = 2;
    if (ws_size >= need(8)) P = 8;
    else if (ws_size >= need(4)) P = 4;

    int*   flag = (int*)d_ws;
    float* A  = (float*)d_ws + 64;
    float* Bb = A + NX;
    float* T  = Bb + NX;                       // P slices, fp32 (pre-mished)
    bf16*  Vv = (bf16*)(T + (size_t)P * NT);   // P slices, bf16
    bf16*  wexp = Vv + (size_t)P * NV;
    bf16*  vbt  = wexp + (size_t)I3_ * KE_;    // P slices, 6-row zero pad each
    bf16*  xbt  = vbt + (size_t)P * VSTR;      // P slices
    bf16*  wb0  = xbt + (size_t)P * S_ * F_;
    bf16*  wb2  = wb0 + (size_t)I3_ * F_;

    detect_kernel<<<1, 256, 0, stream>>>(flag, (const unsigned short*)emb);
    embed_kernel<<<dim3((unsigned)(NX / 256)), 256, 0, stream>>>(A, Bb, inp, emb, flag);
    zeropad_kernel<<<dim3((P * 6 * I_ + 255) / 256), 256, 0, stream>>>(vbt, P);

    const unsigned WPREP_GRID = (I3_ * I_ + I3_ * F_ + F_ * I_ + 255) / 256;
    int swap = 0;
    for (int d = 0; d < D_; ++d) {
        wprep_kernel<<<dim3(WPREP_GRID), 256, 0, stream>>>(
            wexp, wb0, wb2, w1, w0, w2,
            (size_t)d * I3_ * I_ * K_, (size_t)d * I3_ * F_,
            (size_t)d * F_ * I_, flag);
        for (int bp = 0; bp < B_ / P; ++bp) {
            float* x0 = (swap ? Bb : A) + (size_t)(P * bp) * F_ * S_;
            float* x1 = (swap ? A : Bb) + (size_t)(P * bp) * F_ * S_;
            // xbt[z] = x1(b)^T bf16
            trans_kernel<<<dim3(S_ / 64, F_ / 64, P), 256, 0, stream>>>(
                xbt, (size_t)S_ * F_, x1, (size_t)F_ * S_, F_);
            // T[z] = mish(wb0 @ xbt[z])   (192x256-tile, grid 16*8*P = 512)
            gemm192_kernel<<<dim3(S_ / 256, I3_ / 192, P), 512, 0, stream>>>(
                T, NT, wb0, F_, xbt, (size_t)S_ * F_, F_, F_, 0, 1);
            scan_kernel<<<dim3(I_, P), 256, 0, stream>>>(Vv, T);
            // vbt[z] rows 6.. = Vv[z]^T (pad rows 0..5 stay zero)
            transb_kernel<<<dim3(S_ / 64, I_ / 64, P), 256, 0, stream>>>(
                vbt + 6 * I_, VSTR, Vv, NV, I_);
            // T[z] = mish(causal conv as flattened-K GEMM)
            gemm192_kernel<<<dim3(S_ / 256, I3_ / 192, P), 512, 0, stream>>>(
                T, NT, wexp, KE_, vbt, VSTR, I_, KE_, 1, 1);
            scan_kernel<<<dim3(I_, P), 256, 0, stream>>>(Vv, T);
            transb_kernel<<<dim3(S_ / 64, I_ / 64, P), 256, 0, stream>>>(
                vbt + 6 * I_, VSTR, Vv, NV, I_);
            // x0(b) += wb2 @ v[z]   (128-tile 2-barrier, grid 32*2*P = 256)
            gemm128_kernel<<<dim3(S_ / 128, F_ / 128, P), 256, 0, stream>>>(
                x0, (size_t)F_ * S_, wb2, I_, vbt + 6 * I_, VSTR, I_, I_, 0, 1);
        }
        swap ^= 1;
    }
    final_kernel<<<dim3(S_ / 64, V_ / 64, B_), 256, 0, stream>>>(d_out, A, Bb, outw, outb, flag);
    (void)in_sizes; (void)n_in; (void)out_size;
}

// Round 9
// 2506.342 us; speedup vs baseline: 1.1592x; 1.0567x over previous
//
#include <hip/hip_runtime.h>
#include <hip/hip_bf16.h>

#define B_ 8
#define S_ 4096
#define F_ 256
#define I_ 512
#define D_ 4
#define K_ 7
#define V_ 256
#define I3_ 1536
#define KE_ 3584           // 7*512 flattened causal-conv K
#define VR_ (S_ + 8)       // vbt rows: 6 zero-pad + 4096 + 2 slack

using bf16 = __hip_bfloat16;
typedef __bf16 bf16x8 __attribute__((ext_vector_type(8)));
typedef float  f32x4  __attribute__((ext_vector_type(4)));

#define LDS_PTR(p) ((__attribute__((address_space(3))) void*)(p))
#define GLB_PTR(p) ((const __attribute__((address_space(1))) void*)(p))

#define BARR_()  __builtin_amdgcn_s_barrier()
#define WLGKM_() asm volatile("s_waitcnt lgkmcnt(0)" ::: "memory")
#define WVM0_()  asm volatile("s_waitcnt vmcnt(0)" ::: "memory")

// mish(x) = x*tanh(softplus(x)) = x*(u^2+2u)/(u^2+2u+2), u=e^x (exact closed form).
__device__ __forceinline__ float mishf(float x) {
    float u = expf(fminf(x, 30.0f));
    float t = u * (u + 2.0f);
    return x * (t / (t + 2.0f));
}

__device__ __forceinline__ float loadw(const void* p, size_t i, int isbf) {
    return isbf ? __bfloat162float(((const bf16*)p)[i]) : ((const float*)p)[i];
}

__device__ __forceinline__ __bf16 tobf(float x) {
    bf16 h = __float2bfloat16(x);
    return *(__bf16*)&h;
}

__device__ __forceinline__ float bf2f(__bf16 h) {
    unsigned short u = __builtin_bit_cast(unsigned short, h);
    unsigned int x = (unsigned int)u << 16;
    return __builtin_bit_cast(float, x);
}

// bf16 buffers of small weights never show bf16-exponent>=132 (|x|>=32);
// fp32 buffers read as uint16 do (random mantissa bits in low halves).
__global__ __launch_bounds__(256)
void detect_kernel(int* __restrict__ flag, const unsigned short* __restrict__ p)
{
    __shared__ int sh[256];
    int cnt = 0;
    for (int j = threadIdx.x; j < 16384; j += 256) {
        unsigned int e = (p[j] >> 7) & 0xffu;
        if (e >= 132u) cnt++;
    }
    sh[threadIdx.x] = cnt;
    __syncthreads();
    for (int s = 128; s > 0; s >>= 1) {
        if ((int)threadIdx.x < s) sh[threadIdx.x] += sh[threadIdx.x + s];
        __syncthreads();
    }
    if (threadIdx.x == 0) flag[0] = (sh[0] == 0) ? 1 : 0;   // 1 => bf16 inputs
}

__global__ __launch_bounds__(256)
void embed_kernel(float* __restrict__ x0, float* __restrict__ x1,
                  const int* __restrict__ inp, const void* __restrict__ emb,
                  const int* __restrict__ flag)
{
    const int isbf = flag[0];
    size_t idx = (size_t)blockIdx.x * 256 + threadIdx.x;   // over B*F*S
    int s = (int)(idx % S_);
    int f = (int)((idx / S_) % F_);
    int b = (int)(idx / ((size_t)S_ * F_));
    int tok = inp[b * S_ + s];
    x0[idx] = loadw(emb, (size_t)tok * (2 * F_) + f, isbf);
    x1[idx] = loadw(emb, (size_t)tok * (2 * F_) + F_ + f, isbf);
}

// zero the 6 pad rows of all P vbt slices (re-poisoned every call)
__global__ __launch_bounds__(256)
void zeropad_kernel(bf16* __restrict__ vbt, int nslice)
{
    int i = blockIdx.x * 256 + threadIdx.x;
    if (i < nslice * 6 * I_) {
        int z = i / (6 * I_), off = i % (6 * I_);
        vbt[(size_t)z * VR_ * I_ + off] = __float2bfloat16(0.0f);
    }
}

// merged per-depth weight prep (one dispatch instead of three):
//   job 0: wexp [o][k*512+c] <- w1 [o][c][k]   (I3*I indices)
//   job 1: wb0[i] <- (bf16)w0[o0w + i]         (I3*F indices)
//   job 2: wb2[i] <- (bf16)w2[o2w + i]         (F*I indices)
__global__ __launch_bounds__(256)
void wprep_kernel(bf16* __restrict__ wexp, bf16* __restrict__ wb0,
                  bf16* __restrict__ wb2, const void* __restrict__ w1,
                  const void* __restrict__ w0, const void* __restrict__ w2,
                  size_t o1w, size_t o0w, size_t o2w, const int* __restrict__ flag)
{
    const int isbf = flag[0];
    int idx = blockIdx.x * 256 + threadIdx.x;
    if (idx < I3_ * I_) {
        int c = idx & 511, o = idx >> 9;
        const size_t base = o1w + ((size_t)o * 512 + c) * 7;
        float vals[7];
        #pragma unroll
        for (int k = 0; k < 7; ++k) vals[k] = loadw(w1, base + k, isbf);
        #pragma unroll
        for (int k = 0; k < 7; ++k)
            wexp[(size_t)o * KE_ + (k << 9) + c] = __float2bfloat16(vals[k]);
    } else if (idx < I3_ * I_ + I3_ * F_) {
        int i = idx - I3_ * I_;
        wb0[i] = __float2bfloat16(loadw(w0, o0w + i, isbf));
    } else if (idx < I3_ * I_ + I3_ * F_ + F_ * I_) {
        int i = idx - I3_ * I_ - I3_ * F_;
        wb2[i] = __float2bfloat16(loadw(w2, o2w + i, isbf));
    }
}

// Inputs are PRE-MISHED by the gemm epilogue; SPLIT layout:
//   td [I][S] fp32  = depth plane (cumsum operand, kept fp32)
//   tb [2I][S] bf16 = scale plane (rows 0..I-1) then shift plane (rows I..)
// v[i,s] = cumsum_s(td[i,s])/(s+1) * tb[i,s] + tb[I+i,s]; bf16 output.
// grid (I_, P): blockIdx.y = z scratch slice
__global__ __launch_bounds__(256)
void scan_kernel(bf16* __restrict__ vout, const float* __restrict__ td,
                 const bf16* __restrict__ tb)
{
    const int z = blockIdx.y;
    const int i = blockIdx.x;
    td   += (size_t)z * I_ * S_;
    tb   += (size_t)z * 2 * I_ * S_;
    vout += (size_t)z * I_ * S_;
    const float* dp = td + (size_t)i * S_;
    const bf16* scp = tb + (size_t)i * S_;
    const bf16* shp = tb + (size_t)(I_ + i) * S_;
    bf16* op = vout + (size_t)i * S_;
    const int tid = threadIdx.x;
    const int base = tid * 16;

    float md[16];
    float lsum = 0.f;
    #pragma unroll
    for (int q = 0; q < 4; ++q) {
        float4 dv = *(const float4*)(dp + base + q * 4);
        #pragma unroll
        for (int j = 0; j < 4; ++j) {
            float m = (&dv.x)[j];
            md[q * 4 + j] = m;
            lsum += m;
        }
    }
    float ssum = lsum;
    #pragma unroll
    for (int off = 1; off < 64; off <<= 1) {
        float nv = __shfl_up(ssum, off, 64);
        if ((tid & 63) >= off) ssum += nv;
    }
    __shared__ float wtot[4];
    const int wid = tid >> 6, lane = tid & 63;
    if (lane == 63) wtot[wid] = ssum;
    __syncthreads();
    float excl = ssum - lsum;
    #pragma unroll
    for (int wq = 0; wq < 3; ++wq)
        if (wq < wid) excl += wtot[wq];

    bf16x8 scv0 = *(const bf16x8*)(const void*)(scp + base);
    bf16x8 scv1 = *(const bf16x8*)(const void*)(scp + base + 8);
    bf16x8 shv0 = *(const bf16x8*)(const void*)(shp + base);
    bf16x8 shv1 = *(const bf16x8*)(const void*)(shp + base + 8);

    float run = excl;
    bf16x8 o0v, o1v;
    #pragma unroll
    for (int e = 0; e < 16; ++e) {
        run += md[e];
        float sdiv = (float)(base + e + 1);
        float sc = bf2f((e < 8) ? scv0[e] : scv1[e - 8]);
        float sh = bf2f((e < 8) ? shv0[e] : shv1[e - 8]);
        float ov = run / sdiv * sc + sh;
        if (e < 8) o0v[e] = tobf(ov);
        else       o1v[e - 8] = tobf(ov);
    }
    *(bf16x8*)(void*)(op + base) = o0v;
    *(bf16x8*)(void*)(op + base + 8) = o1v;
}

// src fp32 [C][S_] (+z*szstr) -> dst bf16 [S_][C] (+z*dzstr); 64x64 LDS tile
__global__ __launch_bounds__(256)
void trans_kernel(bf16* __restrict__ dst, size_t dzstr,
                  const float* __restrict__ src, size_t szstr, int C)
{
    __shared__ __align__(16) bf16 lt[64][72];
    const int z = blockIdx.z;
    dst += (size_t)z * dzstr;
    src += (size_t)z * szstr;
    const int tid = threadIdx.x;
    const int s0 = blockIdx.x * 64;
    const int c0 = blockIdx.y * 64;
    #pragma unroll
    for (int p = 0; p < 4; ++p) {
        int c = p * 16 + (tid >> 4);
        int sc = (tid & 15) * 4;
        float4 f = *(const float4*)(src + (size_t)(c0 + c) * S_ + s0 + sc);
        #pragma unroll
        for (int j = 0; j < 4; ++j)
            lt[sc + j][c] = __float2bfloat16((&f.x)[j]);
    }
    __syncthreads();
    #pragma unroll
    for (int p = 0; p < 2; ++p) {
        int ch = p * 256 + tid;
        int r = ch >> 3, g = ch & 7;
        *(bf16x8*)(dst + (size_t)(s0 + r) * C + c0 + g * 8) =
            *(const bf16x8*)&lt[r][g * 8];
    }
}

// src bf16 [C][S_] (+z*szstr) -> dst bf16 [S_][C] (+z*dzstr); 64x64 LDS tile
__global__ __launch_bounds__(256)
void transb_kernel(bf16* __restrict__ dst, size_t dzstr,
                   const bf16* __restrict__ src, size_t szstr, int C)
{
    __shared__ __align__(16) bf16 lt[64][72];
    const int z = blockIdx.z;
    dst += (size_t)z * dzstr;
    src += (size_t)z * szstr;
    const int tid = threadIdx.x;
    const int s0 = blockIdx.x * 64;
    const int c0 = blockIdx.y * 64;
    #pragma unroll
    for (int p = 0; p < 2; ++p) {
        int c = p * 32 + (tid >> 3);
        int sc = (tid & 7) * 8;
        bf16x8 v = *(const bf16x8*)(src + (size_t)(c0 + c) * S_ + s0 + sc);
        #pragma unroll
        for (int j = 0; j < 8; ++j)
            *(__bf16*)&lt[sc + j][c] = v[j];
    }
    __syncthreads();
    #pragma unroll
    for (int p = 0; p < 2; ++p) {
        int ch = p * 256 + tid;
        int r = ch >> 3, g = ch & 7;
        *(bf16x8*)(dst + (size_t)(s0 + r) * C + c0 + g * 8) =
            *(const bf16x8*)&lt[r][g * 8];
    }
}

// ---------------------------------------------------------------------------
// 192(o) x 256(s) tile GEMM (P<=4 path), double-buffered LDS (112 KiB), two
// phases / two barriers per K-tile (R7-verified schedule). Grid 16 x 8 x P.
// Epilogue: mish, SPLIT write: og<I -> outd fp32 (depth plane);
// og>=I -> outb bf16 (scale/shift planes, row og-I).
// ---------------------------------------------------------------------------
__global__ __launch_bounds__(512, 1)
void gemm192_kernel(float* __restrict__ outd, bf16* __restrict__ outb,
                    const bf16* __restrict__ Aw, int lda,
                    const bf16* __restrict__ Bm, size_t bzstr, int ldb,
                    int Kdim, int conv)
{
    __shared__ __align__(16) bf16 la[2][192][64];   // 48 KiB
    __shared__ __align__(16) bf16 lb[2][256][64];   // 64 KiB  (112 total)
    const int tid = threadIdx.x;
    const int s0 = blockIdx.x * 256;
    const int o0 = blockIdx.y * 192;
    const int z  = blockIdx.z;
    outd += (size_t)z * I_ * S_;
    outb += (size_t)z * 2 * I_ * S_;
    Bm   += (size_t)z * bzstr;
    const int wv = tid >> 6, lane = tid & 63;
    const int wr = wv >> 2, wc = wv & 3;            // 2(M) x 4(N) waves
    const int l16 = lane & 15, q = lane >> 4;
    const int srow = lane >> 3;
    const int schunk = (lane & 7) ^ srow;
    const int nKt = Kdim >> 6;

    f32x4 acc[6][4];
    #pragma unroll
    for (int i = 0; i < 6; ++i)
        #pragma unroll
        for (int j = 0; j < 4; ++j)
            #pragma unroll
            for (int r = 0; r < 4; ++r) acc[i][j][r] = 0.f;

#define STAGE_A3(buf, kt) do {                                                \
    const bf16* gpA_ = Aw + (size_t)(o0 + wv * 8 + srow) * lda                \
                          + ((kt) << 6) + (schunk << 3);                      \
    __builtin_amdgcn_global_load_lds(GLB_PTR(gpA_),                           \
        LDS_PTR(&la[buf][wv * 8][0]), 16, 0, 0);                              \
    __builtin_amdgcn_global_load_lds(GLB_PTR(gpA_ + (size_t)64 * lda),        \
        LDS_PTR(&la[buf][64 + wv * 8][0]), 16, 0, 0);                         \
    __builtin_amdgcn_global_load_lds(GLB_PTR(gpA_ + (size_t)128 * lda),       \
        LDS_PTR(&la[buf][128 + wv * 8][0]), 16, 0, 0);                        \
} while (0)

#define STAGE_BL(buf, l, ro, bk) do {                                         \
    const bf16* gpB_ = Bm + (size_t)(s0 + (l) * 64 + wv * 8 + srow + (ro)) * ldb \
                          + (bk) + (schunk << 3);                             \
    __builtin_amdgcn_global_load_lds(GLB_PTR(gpB_),                           \
        LDS_PTR(&lb[buf][(l) * 64 + wv * 8][0]), 16, 0, 0);                   \
} while (0)

#define LDAF6(buf, kk) do {                                                   \
    _Pragma("unroll") for (int i2 = 0; i2 < 6; ++i2) {                        \
        int r_ = wr * 96 + i2 * 16 + l16;                                     \
        af[i2] = *(const bf16x8*)&la[buf][r_][(((kk) * 4 + q) ^ (r_ & 7)) << 3]; \
    }                                                                         \
} while (0)

#define LDBF4(buf, kk) do {                                                   \
    _Pragma("unroll") for (int j2 = 0; j2 < 4; ++j2) {                        \
        int r_ = wc * 64 + j2 * 16 + l16;                                     \
        bfr[j2] = *(const bf16x8*)&lb[buf][r_][(((kk) * 4 + q) ^ (r_ & 7)) << 3]; \
    }                                                                         \
} while (0)

#define MFMA24() do {                                                         \
    __builtin_amdgcn_s_setprio(1);                                            \
    _Pragma("unroll") for (int i2 = 0; i2 < 6; ++i2)                          \
    _Pragma("unroll") for (int j2 = 0; j2 < 4; ++j2)                          \
        acc[i2][j2] = __builtin_amdgcn_mfma_f32_16x16x32_bf16(                \
            af[i2], bfr[j2], acc[i2][j2], 0, 0, 0);                           \
    __builtin_amdgcn_s_setprio(0);                                            \
} while (0)

    STAGE_A3(0, 0);
    STAGE_BL(0, 0, 0, 0); STAGE_BL(0, 1, 0, 0);
    STAGE_BL(0, 2, 0, 0); STAGE_BL(0, 3, 0, 0);
    WVM0_();
    BARR_();

    bf16x8 af[6], bfr[4];
    for (int t = 0; t < nKt; ++t) {
        const int c = t & 1, n = c ^ 1;
        const bool st = (t + 1) < nKt;
        int ro1 = 0, bk1 = (t + 1) << 6;
        if (conv) { ro1 = bk1 >> 9; bk1 &= 511; }
        LDAF6(c, 0); LDBF4(c, 0);
        if (st) {
            STAGE_A3(n, t + 1);
            STAGE_BL(n, 0, ro1, bk1); STAGE_BL(n, 1, ro1, bk1);
            STAGE_BL(n, 2, ro1, bk1); STAGE_BL(n, 3, ro1, bk1);
        }
        BARR_(); WLGKM_();
        MFMA24();
        LDAF6(c, 1); LDBF4(c, 1);
        if (st) WVM0_();
        BARR_(); WLGKM_();
        MFMA24();
    }

    // C/D: col(lane&15)=s, row(q*4+reg)=o   [verified convention]
    #pragma unroll
    for (int i = 0; i < 6; ++i)
        #pragma unroll
        for (int j = 0; j < 4; ++j) {
            int sg = s0 + wc * 64 + j * 16 + l16;
            #pragma unroll
            for (int r = 0; r < 4; ++r) {
                int og = o0 + wr * 96 + i * 16 + q * 4 + r;
                float v = mishf(acc[i][j][r]);
                if (og < I_) outd[(size_t)og * S_ + sg] = v;
                else outb[(size_t)(og - I_) * S_ + sg] = __float2bfloat16(v);
            }
        }
#undef STAGE_A3
#undef STAGE_BL
#undef LDAF6
#undef LDBF4
#undef MFMA24
}

// ---------------------------------------------------------------------------
// 256 x 256 tile GEMM (P=8 path): per-wave 128x64, acc[8][4], 128 KiB LDS,
// same 2-phase / 2-barrier schedule as gemm192 (hazard audit identical).
// Grid 16 x 6 x 8 = 768 = exactly 3 rounds over 256 CUs.
// Better compute/LDS-traffic ratio: MFMA 621 cyc vs LDS 765 cyc per K-tile
// (81% ceiling vs 73% at 192-tile). Split mish epilogue as gemm192.
// ---------------------------------------------------------------------------
__global__ __launch_bounds__(512, 1)
void gemm256_kernel(float* __restrict__ outd, bf16* __restrict__ outb,
                    const bf16* __restrict__ Aw, int lda,
                    const bf16* __restrict__ Bm, size_t bzstr, int ldb,
                    int Kdim, int conv)
{
    __shared__ __align__(16) bf16 la[2][256][64];   // 64 KiB
    __shared__ __align__(16) bf16 lb[2][256][64];   // 64 KiB (128 total)
    const int tid = threadIdx.x;
    const int s0 = blockIdx.x * 256;
    const int o0 = blockIdx.y * 256;
    const int z  = blockIdx.z;
    outd += (size_t)z * I_ * S_;
    outb += (size_t)z * 2 * I_ * S_;
    Bm   += (size_t)z * bzstr;
    const int wv = tid >> 6, lane = tid & 63;
    const int wr = wv >> 2, wc = wv & 3;            // 2(M) x 4(N) waves
    const int l16 = lane & 15, q = lane >> 4;
    const int srow = lane >> 3;
    const int schunk = (lane & 7) ^ srow;
    const int nKt = Kdim >> 6;

    f32x4 acc[8][4];
    #pragma unroll
    for (int i = 0; i < 8; ++i)
        #pragma unroll
        for (int j = 0; j < 4; ++j)
            #pragma unroll
            for (int r = 0; r < 4; ++r) acc[i][j][r] = 0.f;

#define STAGE_A4(buf, kt) do {                                                \
    const bf16* gpA_ = Aw + (size_t)(o0 + wv * 8 + srow) * lda                \
                          + ((kt) << 6) + (schunk << 3);                      \
    __builtin_amdgcn_global_load_lds(GLB_PTR(gpA_),                           \
        LDS_PTR(&la[buf][wv * 8][0]), 16, 0, 0);                              \
    __builtin_amdgcn_global_load_lds(GLB_PTR(gpA_ + (size_t)64 * lda),        \
        LDS_PTR(&la[buf][64 + wv * 8][0]), 16, 0, 0);                         \
    __builtin_amdgcn_global_load_lds(GLB_PTR(gpA_ + (size_t)128 * lda),       \
        LDS_PTR(&la[buf][128 + wv * 8][0]), 16, 0, 0);                        \
    __builtin_amdgcn_global_load_lds(GLB_PTR(gpA_ + (size_t)192 * lda),       \
        LDS_PTR(&la[buf][192 + wv * 8][0]), 16, 0, 0);                        \
} while (0)

#define STAGE_BL2(buf, l, ro, bk) do {                                        \
    const bf16* gpB_ = Bm + (size_t)(s0 + (l) * 64 + wv * 8 + srow + (ro)) * ldb \
                          + (bk) + (schunk << 3);                             \
    __builtin_amdgcn_global_load_lds(GLB_PTR(gpB_),                           \
        LDS_PTR(&lb[buf][(l) * 64 + wv * 8][0]), 16, 0, 0);                   \
} while (0)

#define LDAF8(buf, kk) do {                                                   \
    _Pragma("unroll") for (int i2 = 0; i2 < 8; ++i2) {                        \
        int r_ = wr * 128 + i2 * 16 + l16;                                    \
        af[i2] = *(const bf16x8*)&la[buf][r_][(((kk) * 4 + q) ^ (r_ & 7)) << 3]; \
    }                                                                         \
} while (0)

#define LDBF4B(buf, kk) do {                                                  \
    _Pragma("unroll") for (int j2 = 0; j2 < 4; ++j2) {                        \
        int r_ = wc * 64 + j2 * 16 + l16;                                     \
        bfr[j2] = *(const bf16x8*)&lb[buf][r_][(((kk) * 4 + q) ^ (r_ & 7)) << 3]; \
    }                                                                         \
} while (0)

#define MFMA32() do {                                                         \
    __builtin_amdgcn_s_setprio(1);                                            \
    _Pragma("unroll") for (int i2 = 0; i2 < 8; ++i2)                          \
    _Pragma("unroll") for (int j2 = 0; j2 < 4; ++j2)                          \
        acc[i2][j2] = __builtin_amdgcn_mfma_f32_16x16x32_bf16(                \
            af[i2], bfr[j2], acc[i2][j2], 0, 0, 0);                           \
    __builtin_amdgcn_s_setprio(0);                                            \
} while (0)

    STAGE_A4(0, 0);
    STAGE_BL2(0, 0, 0, 0); STAGE_BL2(0, 1, 0, 0);
    STAGE_BL2(0, 2, 0, 0); STAGE_BL2(0, 3, 0, 0);
    WVM0_();
    BARR_();

    bf16x8 af[8], bfr[4];
    for (int t = 0; t < nKt; ++t) {
        const int c = t & 1, n = c ^ 1;
        const bool st = (t + 1) < nKt;
        int ro1 = 0, bk1 = (t + 1) << 6;
        if (conv) { ro1 = bk1 >> 9; bk1 &= 511; }
        LDAF8(c, 0); LDBF4B(c, 0);
        if (st) {
            STAGE_A4(n, t + 1);
            STAGE_BL2(n, 0, ro1, bk1); STAGE_BL2(n, 1, ro1, bk1);
            STAGE_BL2(n, 2, ro1, bk1); STAGE_BL2(n, 3, ro1, bk1);
        }
        BARR_(); WLGKM_();
        MFMA32();
        LDAF8(c, 1); LDBF4B(c, 1);
        if (st) WVM0_();
        BARR_(); WLGKM_();
        MFMA32();
    }

    #pragma unroll
    for (int i = 0; i < 8; ++i)
        #pragma unroll
        for (int j = 0; j < 4; ++j) {
            int sg = s0 + wc * 64 + j * 16 + l16;
            #pragma unroll
            for (int r = 0; r < 4; ++r) {
                int og = o0 + wr * 128 + i * 16 + q * 4 + r;
                float v = mishf(acc[i][j][r]);
                if (og < I_) outd[(size_t)og * S_ + sg] = v;
                else outb[(size_t)(og - I_) * S_ + sg] = __float2bfloat16(v);
            }
        }
#undef STAGE_A4
#undef STAGE_BL2
#undef LDAF8
#undef LDBF4B
#undef MFMA32
}

// 128x128 GEMM for the small w2 conv (M=256) + accumulate.
// Double-buffered 2-barrier schedule. Grid = 32 x 2 x P.
__global__ __launch_bounds__(256)
void gemm128_kernel(float* __restrict__ out, size_t ozstr,
                    const bf16* __restrict__ Aw, int lda,
                    const bf16* __restrict__ Bm, size_t bzstr, int ldb,
                    int Kdim, int conv, int addres)
{
    __shared__ __align__(16) bf16 la[2][128][64];   // 32 KiB
    __shared__ __align__(16) bf16 lb[2][128][64];   // 32 KiB (64 total)
    const int tid = threadIdx.x;
    const int s0 = blockIdx.x * 128;
    const int o0 = blockIdx.y * 128;
    const int z  = blockIdx.z;
    out += (size_t)z * ozstr;
    Bm  += (size_t)z * bzstr;
    const int wv = tid >> 6, lane = tid & 63;
    const int wo = wv & 1, wsv = wv >> 1;
    const int l16 = lane & 15, q = lane >> 4;
    const int lrow = lane >> 3, lslot = lane & 7;
    const int nKt = Kdim >> 6;

    f32x4 acc[4][4];
    #pragma unroll
    for (int i = 0; i < 4; ++i)
        #pragma unroll
        for (int j = 0; j < 4; ++j)
            #pragma unroll
            for (int r = 0; r < 4; ++r) acc[i][j][r] = 0.f;

#define G128_STAGE(buf, kt) do {                                              \
    int k0_ = (kt) << 6; int roff_ = 0, bk_ = k0_;                            \
    if (conv) { roff_ = k0_ >> 9; bk_ = k0_ & 511; }                          \
    _Pragma("unroll") for (int t_ = 0; t_ < 4; ++t_) {                        \
        int rbase = wv * 32 + t_ * 8;                                         \
        int row = rbase + lrow;                                               \
        int chunk = lslot ^ (row & 7);                                        \
        __builtin_amdgcn_global_load_lds(                                     \
            GLB_PTR(Aw + (size_t)(o0 + row) * lda + k0_ + chunk * 8),         \
            LDS_PTR(&la[buf][rbase][0]), 16, 0, 0);                           \
        __builtin_amdgcn_global_load_lds(                                     \
            GLB_PTR(Bm + (size_t)(s0 + row + roff_) * ldb + bk_ + chunk * 8), \
            LDS_PTR(&lb[buf][rbase][0]), 16, 0, 0);                           \
    }                                                                         \
} while (0)

#define G128_RD(buf, kk) do {                                                 \
    _Pragma("unroll") for (int i = 0; i < 4; ++i) {                           \
        int r = wo * 64 + i * 16 + l16;                                       \
        af[i] = *(const bf16x8*)&la[buf][r][(((kk) * 4 + q) ^ (r & 7)) * 8];  \
    }                                                                         \
    _Pragma("unroll") for (int j = 0; j < 4; ++j) {                           \
        int r = wsv * 64 + j * 16 + l16;                                      \
        bfr[j] = *(const bf16x8*)&lb[buf][r][(((kk) * 4 + q) ^ (r & 7)) * 8]; \
    }                                                                         \
} while (0)

#define G128_MFMA16() do {                                                    \
    __builtin_amdgcn_s_setprio(1);                                            \
    _Pragma("unroll") for (int i = 0; i < 4; ++i)                             \
    _Pragma("unroll") for (int j = 0; j < 4; ++j)                             \
        acc[i][j] = __builtin_amdgcn_mfma_f32_16x16x32_bf16(                  \
            af[i], bfr[j], acc[i][j], 0, 0, 0);                               \
    __builtin_amdgcn_s_setprio(0);                                            \
} while (0)

    G128_STAGE(0, 0);
    WVM0_();
    BARR_();

    bf16x8 af[4], bfr[4];
    for (int t = 0; t < nKt; ++t) {
        const int c = t & 1, n = c ^ 1;
        const bool st = (t + 1) < nKt;
        G128_RD(c, 0);
        if (st) G128_STAGE(n, t + 1);
        BARR_(); WLGKM_();
        G128_MFMA16();
        G128_RD(c, 1);
        if (st) WVM0_();
        BARR_(); WLGKM_();
        G128_MFMA16();
    }

    #pragma unroll
    for (int i = 0; i < 4; ++i)
        #pragma unroll
        for (int j = 0; j < 4; ++j) {
            int sg = s0 + wsv * 64 + j * 16 + l16;
            #pragma unroll
            for (int r = 0; r < 4; ++r) {
                int og = o0 + wo * 64 + i * 16 + q * 4 + r;
                float v = acc[i][j][r];
                if (addres) v += out[(size_t)og * S_ + sg];
                out[(size_t)og * S_ + sg] = v;
            }
        }
#undef G128_STAGE
#undef G128_RD
#undef G128_MFMA16
}

__global__ __launch_bounds__(256)
void final_kernel(void* __restrict__ out, const float* __restrict__ x0,
                  const float* __restrict__ x1, const void* __restrict__ ow,
                  const void* __restrict__ ob, const int* __restrict__ flag)
{
    __shared__ float wl[16][68];
    __shared__ float xl[16][68];
    const int isbf = flag[0];
    const int tid = threadIdx.x;
    const int tx = tid & 15, ty = tid >> 4;
    const int s0 = blockIdx.x * 64;
    const int o0 = blockIdx.y * 64;
    const int b  = blockIdx.z;
    float acc[4][4] = {};
    for (int c0 = 0; c0 < 2 * F_; c0 += 16) {
        if (isbf) {
            #pragma unroll
            for (int e = tid; e < 1024; e += 256) {
                int k = e & 15, o = e >> 4;
                wl[k][o] = __bfloat162float(((const bf16*)ow)[(size_t)(o0 + o) * (2 * F_) + (c0 + k)]);
            }
        } else {
            #pragma unroll
            for (int e = tid; e < 1024; e += 256) {
                int k = e & 15, o = e >> 4;
                wl[k][o] = ((const float*)ow)[(size_t)(o0 + o) * (2 * F_) + (c0 + k)];
            }
        }
        {
            int r = tid >> 4;
            int qq = (tid & 15) * 4;
            int cr = c0 + r;
            const float* src = (cr < F_) ? (x0 + ((size_t)b * F_ + cr) * S_)
                                         : (x1 + ((size_t)b * F_ + (cr - F_)) * S_);
            *(float4*)&xl[r][qq] = *(const float4*)(src + s0 + qq);
        }
        __syncthreads();
        #pragma unroll
        for (int k = 0; k < 16; ++k) {
            float4 av = *(const float4*)&wl[k][ty * 4];
            float4 bv = *(const float4*)&xl[k][tx * 4];
            #pragma unroll
            for (int i = 0; i < 4; ++i)
                #pragma unroll
                for (int j = 0; j < 4; ++j)
                    acc[i][j] += (&av.x)[i] * (&bv.x)[j];
        }
        __syncthreads();
    }
    #pragma unroll
    for (int i = 0; i < 4; ++i) {
        int o = o0 + ty * 4 + i;
        float bias = loadw(ob, o, isbf);
        size_t outoff = ((size_t)b * V_ + o) * S_ + s0 + tx * 4;
        if (isbf) {
            bf16* po = (bf16*)out + outoff;
            #pragma unroll
            for (int j = 0; j < 4; ++j)
                po[j] = __float2bfloat16(acc[i][j] + bias);
        } else {
            float* po = (float*)out + outoff;
            *(float4*)po = make_float4(acc[i][0] + bias, acc[i][1] + bias,
                                       acc[i][2] + bias, acc[i][3] + bias);
        }
    }
}

extern "C" void kernel_launch(void* const* d_in, const int* in_sizes, int n_in,
                              void* d_out, int out_size, void* d_ws, size_t ws_size,
                              hipStream_t stream)
{
    const int*  inp  = (const int*)d_in[0];
    const void* emb  = d_in[1];
    const void* w0   = d_in[2];
    const void* w1   = d_in[3];
    const void* w2   = d_in[4];
    const void* outw = d_in[5];
    const void* outb = d_in[6];

    const size_t NX = (size_t)B_ * F_ * S_;
    const size_t NIS = (size_t)I_ * S_;       // one I x S plane
    const size_t VSTR = (size_t)VR_ * I_;     // vbt z-stride (elements)

    // P = batch slices per dispatch. Diet layout:
    //   Td fp32 [P][I][S] + Tb bf16 [P][2I][S] + Vv bf16 [P][I][S]
    auto need = [&](int p) -> size_t {
        return 256 + 8 * NX
             + (size_t)4 * p * NIS            // Td
             + (size_t)4 * p * NIS            // Tb (2I*S bf16 = 4*NIS bytes)
             + (size_t)2 * p * NIS            // Vv
             + 2 * ((size_t)I3_ * KE_ + (size_t)p * VSTR + (size_t)p * S_ * F_
                    + (size_t)I3_ * F_ + (size_t)F_ * I_);
    };
    int P = 2;
    if (ws_size >= need(8)) P = 8;
    else if (ws_size >= need(4)) P = 4;

    int*   flag = (int*)d_ws;
    float* A  = (float*)d_ws + 64;
    float* Bb = A + NX;
    float* Td = Bb + NX;                       // P slices fp32 (depth plane)
    bf16*  Tb = (bf16*)(Td + (size_t)P * NIS); // P slices bf16 (scale+shift)
    bf16*  Vv = Tb + (size_t)P * 2 * NIS;      // P slices bf16
    bf16*  wexp = Vv + (size_t)P * NIS;
    bf16*  vbt  = wexp + (size_t)I3_ * KE_;    // P slices, 6-row zero pad each
    bf16*  xbt  = vbt + (size_t)P * VSTR;      // P slices
    bf16*  wb0  = xbt + (size_t)P * S_ * F_;
    bf16*  wb2  = wb0 + (size_t)I3_ * F_;

    detect_kernel<<<1, 256, 0, stream>>>(flag, (const unsigned short*)emb);
    embed_kernel<<<dim3((unsigned)(NX / 256)), 256, 0, stream>>>(A, Bb, inp, emb, flag);
    zeropad_kernel<<<dim3((P * 6 * I_ + 255) / 256), 256, 0, stream>>>(vbt, P);

    const unsigned WPREP_GRID = (I3_ * I_ + I3_ * F_ + F_ * I_ + 255) / 256;
    int swap = 0;
    for (int d = 0; d < D_; ++d) {
        wprep_kernel<<<dim3(WPREP_GRID), 256, 0, stream>>>(
            wexp, wb0, wb2, w1, w0, w2,
            (size_t)d * I3_ * I_ * K_, (size_t)d * I3_ * F_,
            (size_t)d * F_ * I_, flag);
        for (int bp = 0; bp < B_ / P; ++bp) {
            float* x0 = (swap ? Bb : A) + (size_t)(P * bp) * F_ * S_;
            float* x1 = (swap ? A : Bb) + (size_t)(P * bp) * F_ * S_;
            // xbt[z] = x1(b)^T bf16
            trans_kernel<<<dim3(S_ / 64, F_ / 64, P), 256, 0, stream>>>(
                xbt, (size_t)S_ * F_, x1, (size_t)F_ * S_, F_);
            // Td/Tb = mish(wb0 @ xbt[z]) split-plane
            if (P == 8)
                gemm256_kernel<<<dim3(S_ / 256, I3_ / 256, 8), 512, 0, stream>>>(
                    Td, Tb, wb0, F_, xbt, (size_t)S_ * F_, F_, F_, 0);
            else
                gemm192_kernel<<<dim3(S_ / 256, I3_ / 192, P), 512, 0, stream>>>(
                    Td, Tb, wb0, F_, xbt, (size_t)S_ * F_, F_, F_, 0);
            scan_kernel<<<dim3(I_, P), 256, 0, stream>>>(Vv, Td, Tb);
            // vbt[z] rows 6.. = Vv[z]^T (pad rows 0..5 stay zero)
            transb_kernel<<<dim3(S_ / 64, I_ / 64, P), 256, 0, stream>>>(
                vbt + 6 * I_, VSTR, Vv, NIS, I_);
            // Td/Tb = mish(causal conv as flattened-K GEMM)
            if (P == 8)
                gemm256_kernel<<<dim3(S_ / 256, I3_ / 256, 8), 512, 0, stream>>>(
                    Td, Tb, wexp, KE_, vbt, VSTR, I_, KE_, 1);
            else
                gemm192_kernel<<<dim3(S_ / 256, I3_ / 192, P), 512, 0, stream>>>(
                    Td, Tb, wexp, KE_, vbt, VSTR, I_, KE_, 1);
            scan_kernel<<<dim3(I_, P), 256, 0, stream>>>(Vv, Td, Tb);
            transb_kernel<<<dim3(S_ / 64, I_ / 64, P), 256, 0, stream>>>(
                vbt + 6 * I_, VSTR, Vv, NIS, I_);
            // x0(b) += wb2 @ v[z]   (128-tile 2-barrier, grid 32*2*P)
            gemm128_kernel<<<dim3(S_ / 128, F_ / 128, P), 256, 0, stream>>>(
                x0, (size_t)F_ * S_, wb2, I_, vbt + 6 * I_, VSTR, I_, I_, 0, 1);
        }
        swap ^= 1;
    }
    final_kernel<<<dim3(S_ / 64, V_ / 64, B_), 256, 0, stream>>>(d_out, A, Bb, outw, outb, flag);
    (void)in_sizes; (void)n_in; (void)out_size;
}